// Round 6
// baseline (341.421 us; speedup 1.0000x reference)
//
#include <hip/hip_runtime.h>
#include <hip/hip_bf16.h>

typedef __bf16 bf16_t;
typedef __bf16 bf16x8 __attribute__((ext_vector_type(8)));
typedef __bf16 bf16x4 __attribute__((ext_vector_type(4)));
typedef float  f32x4  __attribute__((ext_vector_type(4)));

#define MFMA_BF16 __builtin_amdgcn_mfma_f32_16x16x32_bf16
#define NEG_BIG  (-3.0e38f)

#if __has_builtin(__builtin_amdgcn_exp2f)
#define EXP2F(x) __builtin_amdgcn_exp2f(x)
#else
#define EXP2F(x) exp2f(x)
#endif

#define SBAR()       __builtin_amdgcn_s_barrier()
#define SCHED0()     __builtin_amdgcn_sched_barrier(0)
#define WAIT_LGKM0() asm volatile("s_waitcnt lgkmcnt(0)" ::: "memory")
#define WAIT_LGKM8() asm volatile("s_waitcnt lgkmcnt(8)" ::: "memory")
#define WAIT_VM0()   asm volatile("s_waitcnt vmcnt(0)" ::: "memory")
#define WAIT_VM4()   asm volatile("s_waitcnt vmcnt(4)" ::: "memory")
#define WAIT_VM6()   asm volatile("s_waitcnt vmcnt(6)" ::: "memory")

// async global->LDS 16B copy (gfx950 dwordx4 variant)
__device__ __forceinline__ void load16_lds(const bf16_t* g, bf16_t* l) {
    __builtin_amdgcn_global_load_lds(
        (const __attribute__((address_space(1))) void*)g,
        (__attribute__((address_space(3))) void*)l, 16, 0, 0);
}

// load 8 contiguous elements as bf16x8, converting if source is fp32
__device__ inline bf16x8 ld8(const bf16_t* p) { return *(const bf16x8*)p; }
__device__ inline bf16x8 ld8(const float* p) {
    f32x4 a = *(const f32x4*)p;
    f32x4 b = *(const f32x4*)(p + 4);
    bf16x8 o;
    o[0] = (bf16_t)a[0]; o[1] = (bf16_t)a[1]; o[2] = (bf16_t)a[2]; o[3] = (bf16_t)a[3];
    o[4] = (bf16_t)b[0]; o[5] = (bf16_t)b[1]; o[6] = (bf16_t)b[2]; o[7] = (bf16_t)b[3];
    return o;
}

// ---------------------------------------------------------------------------
// LoRA first stage body: out[m][r] = sum_k X[m][k] * A[r][k]
// ---------------------------------------------------------------------------
template <typename TX>
__device__ __forceinline__ void lora_xa_body(
    const TX* __restrict__ X, const float* __restrict__ A,
    float* __restrict__ out, int m, int lane)
{
    const TX* xp = X + (size_t)m * 1024;
    float acc[8];
#pragma unroll
    for (int r = 0; r < 8; r++) acc[r] = 0.f;

#pragma unroll 4
    for (int ci = 0; ci < 16; ci++) {
        int k = ci * 64 + lane;
        float xv = (float)xp[k];
#pragma unroll
        for (int r = 0; r < 8; r++) acc[r] += xv * A[r * 1024 + k];
    }
#pragma unroll
    for (int r = 0; r < 8; r++) {
        float v = acc[r];
        v += __shfl_xor(v, 1);  v += __shfl_xor(v, 2);  v += __shfl_xor(v, 4);
        v += __shfl_xor(v, 8);  v += __shfl_xor(v, 16); v += __shfl_xor(v, 32);
        if (lane == 0) out[m * 8 + r] = v;
    }
}

template <typename TX>
__global__ __launch_bounds__(256) void lora_xa_kernel(
    const TX* __restrict__ X, const float* __restrict__ A,
    float* __restrict__ out)
{
    const int lane = threadIdx.x & 63;
    const int w    = threadIdx.x >> 6;
    const int m    = blockIdx.x * 4 + w;
    lora_xa_body<TX>(X, A, out, m, lane);
}

// ---------------------------------------------------------------------------
// Fused prep: fp32->bf16 converts for x / Wqkv / Wproj + first-stage LoRA
// + zero xa2 (blocks 8192..8199) for the fused attn accumulation.
// ---------------------------------------------------------------------------
__global__ __launch_bounds__(256) void prep_kernel(
    const float* __restrict__ x, const float* __restrict__ Wqkv,
    const float* __restrict__ Wproj,
    bf16_t* __restrict__ x16, bf16_t* __restrict__ Wqkv16,
    bf16_t* __restrict__ Wproj16,
    const float* __restrict__ Aqkv, float* __restrict__ xa1,
    float* __restrict__ xa2)
{
    const int bid = blockIdx.x;
    if (bid < 6144) {
        const float* in; bf16_t* out; size_t off;
        if (bid < 4096)      { in = x;     out = x16;     off = (size_t)bid * 2048; }
        else if (bid < 5632) { in = Wqkv;  out = Wqkv16;  off = (size_t)(bid - 4096) * 2048; }
        else                 { in = Wproj; out = Wproj16; off = (size_t)(bid - 5632) * 2048; }
        size_t i = off + (size_t)threadIdx.x * 8;
        *(bf16x8*)&out[i] = ld8(&in[i]);
    } else if (bid < 8192) {
        const int lane = threadIdx.x & 63;
        const int w    = threadIdx.x >> 6;
        const int m    = (bid - 6144) * 4 + w;
        lora_xa_body<float>(x, Aqkv, xa1, m, lane);
    } else {
        // zero xa2: 8 blocks x 256 thr x 8 floats = 65536 floats... (16384*4B)
        float* p = xa2 + (size_t)(bid - 8192) * 2048 + (size_t)threadIdx.x * 8;
        f32x4 z = {0.f, 0.f, 0.f, 0.f};
        *(f32x4*)&p[0] = z;
        *(f32x4*)&p[4] = z;
    }
}

// ---------------------------------------------------------------------------
// Shared epilogue for 4x4 acc (128-tile kernels) — round-4 proven version.
// ---------------------------------------------------------------------------
__device__ __forceinline__ void gemm_epilogue(
    f32x4 (&acc)[4][4], const float* bias, const float* xA, const float* LB,
    bf16_t* C0, bf16_t* C1, bf16_t* C2, float* Cf,
    int tile_m, int tile_n, int wm, int wn, int c, int g)
{
    const int seg    = tile_n >> 10;
    const int tn_loc = tile_n & 1023;
    bf16_t* Cout = (seg == 0) ? C0 : (seg == 1) ? C1 : C2;

    float biasf[4];
    float lbv[4][8];
#pragma unroll
    for (int j = 0; j < 4; j++) {
        int col = tile_n + wn + j * 16 + c;
        biasf[j] = bias[col];
        f32x4 lb0 = *(const f32x4*)&LB[(size_t)col * 8];
        f32x4 lb1 = *(const f32x4*)&LB[(size_t)col * 8 + 4];
#pragma unroll
        for (int r = 0; r < 4; r++) { lbv[j][r] = lb0[r]; lbv[j][r + 4] = lb1[r]; }
    }
#pragma unroll
    for (int i = 0; i < 4; i++) {
#pragma unroll
        for (int rg = 0; rg < 4; rg++) {
            int row = tile_m + wm + i * 16 + g * 4 + rg;
            f32x4 xa0 = *(const f32x4*)&xA[(size_t)row * 8];
            f32x4 xa1 = *(const f32x4*)&xA[(size_t)row * 8 + 4];
#pragma unroll
            for (int j = 0; j < 4; j++) {
                float lora = xa0[0] * lbv[j][0] + xa0[1] * lbv[j][1] +
                             xa0[2] * lbv[j][2] + xa0[3] * lbv[j][3] +
                             xa1[0] * lbv[j][4] + xa1[1] * lbv[j][5] +
                             xa1[2] * lbv[j][6] + xa1[3] * lbv[j][7];
                float v = acc[i][j][rg] + biasf[j] + 2.0f * lora;
                int lcol = tn_loc + wn + j * 16 + c;
                if (Cf) Cf[(size_t)row * 1024 + lcol] = v;
                else    Cout[(size_t)row * 1024 + lcol] = (bf16_t)v;
            }
        }
    }
}

// ---------------------------------------------------------------------------
// FALLBACK GEMM (small-ws path): VGPR staging, inline fp32->bf16 cvt.
// ---------------------------------------------------------------------------
template <typename TA, typename TW>
__global__ __launch_bounds__(256) void gemm_bias_lora(
    const TA* __restrict__ A, const TW* __restrict__ W,
    const float* __restrict__ bias, const float* __restrict__ xA,
    const float* __restrict__ LB,
    bf16_t* __restrict__ C0, bf16_t* __restrict__ C1, bf16_t* __restrict__ C2,
    float* __restrict__ Cf, int K)
{
    __shared__ __align__(16) bf16_t As[128 * 72];
    __shared__ __align__(16) bf16_t Bs[128 * 72];

    const int t    = threadIdx.x;
    const int lane = t & 63;
    const int w    = t >> 6;
    const int wm   = (w >> 1) * 64;
    const int wn   = (w & 1) * 64;
    const int c    = lane & 15;
    const int g    = lane >> 4;
    const int tile_m = blockIdx.y * 128;
    const int tile_n = blockIdx.x * 128;

    const int srow = t >> 3;
    const int scol = (t & 7) * 8;

    f32x4 acc[4][4];
#pragma unroll
    for (int i = 0; i < 4; i++)
#pragma unroll
        for (int j = 0; j < 4; j++) {
            f32x4 z = {0.f, 0.f, 0.f, 0.f};
            acc[i][j] = z;
        }

    for (int k0 = 0; k0 < K; k0 += 64) {
#pragma unroll
        for (int i = 0; i < 4; i++) {
            int r = srow + i * 32;
            *(bf16x8*)&As[r * 72 + scol] = ld8(&A[(size_t)(tile_m + r) * K + k0 + scol]);
            *(bf16x8*)&Bs[r * 72 + scol] = ld8(&W[(size_t)(tile_n + r) * K + k0 + scol]);
        }
        __syncthreads();

#pragma unroll
        for (int kk = 0; kk < 2; kk++) {
            bf16x8 af[4], bfr[4];
#pragma unroll
            for (int i = 0; i < 4; i++)
                af[i] = *(const bf16x8*)&As[(wm + i * 16 + c) * 72 + kk * 32 + g * 8];
#pragma unroll
            for (int j = 0; j < 4; j++)
                bfr[j] = *(const bf16x8*)&Bs[(wn + j * 16 + c) * 72 + kk * 32 + g * 8];
#pragma unroll
            for (int i = 0; i < 4; i++)
#pragma unroll
                for (int j = 0; j < 4; j++)
                    acc[i][j] = MFMA_BF16(af[i], bfr[j], acc[i][j], 0, 0, 0);
        }
        __syncthreads();
    }
    gemm_epilogue(acc, bias, xA, LB, C0, C1, C2, Cf, tile_m, tile_n, wm, wn, c, g);
}

// ---------------------------------------------------------------------------
// ASYNC GEMM 128x128 (m97 structure) — proj GEMM.  Round-4 proven version.
// ---------------------------------------------------------------------------
#define AS_OFF(row, q) ((row) * 64 + (((q) ^ ((row) & 7)) * 8))

__global__ __launch_bounds__(256) void gemm_async(
    const bf16_t* __restrict__ A, const bf16_t* __restrict__ W,
    const float* __restrict__ bias, const float* __restrict__ xA,
    const float* __restrict__ LB,
    bf16_t* __restrict__ C0, bf16_t* __restrict__ C1, bf16_t* __restrict__ C2,
    float* __restrict__ Cf, int K)
{
    __shared__ __align__(16) bf16_t As[128 * 64];
    __shared__ __align__(16) bf16_t Bs[128 * 64];

    const int t    = threadIdx.x;
    const int lane = t & 63;
    const int w    = t >> 6;
    const int wm   = (w >> 1) * 64;
    const int wn   = (w & 1) * 64;
    const int c    = lane & 15;
    const int g    = lane >> 4;
    const int tile_m = blockIdx.y * 128;
    const int tile_n = blockIdx.x * 128;

    const int trow = t >> 3;                   // 0..31
    const int k8   = (t & 7) ^ (trow & 7);     // swizzled k-chunk for staging
    const bf16_t* Ab = A + (size_t)tile_m * K + k8 * 8;
    const bf16_t* Wb = W + (size_t)tile_n * K + k8 * 8;

    f32x4 acc[4][4];
#pragma unroll
    for (int i = 0; i < 4; i++)
#pragma unroll
        for (int j = 0; j < 4; j++) {
            f32x4 z = {0.f, 0.f, 0.f, 0.f};
            acc[i][j] = z;
        }

    for (int k0 = 0; k0 < K; k0 += 64) {
#pragma unroll
        for (int i = 0; i < 4; i++) {
            int row = i * 32 + trow;
            load16_lds(&Ab[(size_t)row * K + k0], &As[(i * 256 + t) * 8]);
            load16_lds(&Wb[(size_t)row * K + k0], &Bs[(i * 256 + t) * 8]);
        }
        __syncthreads();

#pragma unroll
        for (int kk = 0; kk < 2; kk++) {
            bf16x8 af[4], bfr[4];
#pragma unroll
            for (int i = 0; i < 4; i++)
                af[i] = *(const bf16x8*)&As[AS_OFF(wm + i * 16 + c, kk * 4 + g)];
#pragma unroll
            for (int j = 0; j < 4; j++)
                bfr[j] = *(const bf16x8*)&Bs[AS_OFF(wn + j * 16 + c, kk * 4 + g)];
#pragma unroll
            for (int i = 0; i < 4; i++)
#pragma unroll
                for (int j = 0; j < 4; j++)
                    acc[i][j] = MFMA_BF16(af[i], bfr[j], acc[i][j], 0, 0, 0);
        }
        __syncthreads();
    }
    gemm_epilogue(acc, bias, xA, LB, C0, C1, C2, Cf, tile_m, tile_n, wm, wn, c, g);
}

// ---------------------------------------------------------------------------
// 256x256 GEMM — round-4 proven version (unswapped, inline old epilogue).
// ---------------------------------------------------------------------------
__global__ __launch_bounds__(512, 2) void gemm_256(
    const bf16_t* __restrict__ A, const bf16_t* __restrict__ W,
    const float* __restrict__ bias, const float* __restrict__ xA,
    const float* __restrict__ LB,
    bf16_t* __restrict__ C0, bf16_t* __restrict__ C1, bf16_t* __restrict__ C2,
    float* __restrict__ Cf, int K, int ntn)
{
    __shared__ __align__(16) bf16_t As[4][8192];   // [buf*2+half][128*64]
    __shared__ __align__(16) bf16_t Bs[4][8192];

    const int t    = threadIdx.x;
    const int lane = t & 63;
    const int w    = t >> 6;
    const int c    = lane & 15;
    const int g    = lane >> 4;

    const int nwg = gridDim.x;
    const int cpx = nwg >> 3;
    const int bid = blockIdx.x;
    const int swz = (bid & 7) * cpx + (bid >> 3);
    const int tile_m = (swz / ntn) * 256;
    const int tile_n = (swz % ntn) * 256;

    const int wm  = (w >> 2) * 128;
    const int wn  = (w & 3) * 64;
    const int ha  = w >> 2;
    const int hb  = wn >> 7;
    const int wnl = wn & 127;

    int aoffs[8][2], boffs[4][2];
#pragma unroll
    for (int il = 0; il < 8; il++) {
        int rl = il * 16 + c;
#pragma unroll
        for (int ks = 0; ks < 2; ks++)
            aoffs[il][ks] = rl * 64 + (((ks * 4 + g) ^ (rl & 7)) * 8);
    }
#pragma unroll
    for (int j2 = 0; j2 < 4; j2++) {
        int rl = wnl + j2 * 16 + c;
#pragma unroll
        for (int ks = 0; ks < 2; ks++)
            boffs[j2][ks] = rl * 64 + (((ks * 4 + g) ^ (rl & 7)) * 8);
    }

    const int trow = t >> 3;
    const int qq   = (t & 7) ^ (trow & 7);
    const bf16_t* aO = A + (size_t)(tile_m + trow) * K + qq * 8;
    const bf16_t* wO = W + (size_t)(tile_n + trow) * K + qq * 8;
    const size_t rK64 = (size_t)64 * K;

#define STAGE_A(T, h) do {                                                         \
    load16_lds(aO + (size_t)(h) * 128 * K + (size_t)(T) * 64,                      \
               &As[((T) & 1) * 2 + (h)][t * 8]);                                   \
    load16_lds(aO + (size_t)(h) * 128 * K + rK64 + (size_t)(T) * 64,               \
               &As[((T) & 1) * 2 + (h)][4096 + t * 8]); } while (0)
#define STAGE_B(T, h) do {                                                         \
    load16_lds(wO + (size_t)(h) * 128 * K + (size_t)(T) * 64,                      \
               &Bs[((T) & 1) * 2 + (h)][t * 8]);                                   \
    load16_lds(wO + (size_t)(h) * 128 * K + rK64 + (size_t)(T) * 64,               \
               &Bs[((T) & 1) * 2 + (h)][4096 + t * 8]); } while (0)

    f32x4 acc[8][4];
#pragma unroll
    for (int i = 0; i < 8; i++)
#pragma unroll
        for (int j2 = 0; j2 < 4; j2++) {
            f32x4 z = {0.f, 0.f, 0.f, 0.f};
            acc[i][j2] = z;
        }

    const int NT = K >> 6;

    STAGE_B(0, 0); STAGE_B(0, 1); STAGE_A(0, 0); STAGE_A(0, 1);
    WAIT_VM4();
    STAGE_B(1, 0); STAGE_B(1, 1); STAGE_A(1, 0);
    WAIT_VM6();
    SBAR();

    for (int j = 0; j < NT; j++) {
        const bf16_t* Ab = &As[(j & 1) * 2 + ha][0];
        const bf16_t* Bb = &Bs[(j & 1) * 2 + hb][0];
        bf16x8 bfr[4][2], af0[4], af1[4];

#pragma unroll
        for (int j2 = 0; j2 < 4; j2++) {
            bfr[j2][0] = *(const bf16x8*)&Bb[boffs[j2][0]];
            bfr[j2][1] = *(const bf16x8*)&Bb[boffs[j2][1]];
        }
#pragma unroll
        for (int i = 0; i < 4; i++) af0[i] = *(const bf16x8*)&Ab[aoffs[i][0]];
        if (j + 1 < NT) STAGE_A(j + 1, 1);
        WAIT_LGKM8();
        SBAR();
        WAIT_LGKM0();
        SCHED0();
        __builtin_amdgcn_s_setprio(1);
#pragma unroll
        for (int i = 0; i < 4; i++)
#pragma unroll
            for (int j2 = 0; j2 < 4; j2++)
                acc[i][j2] = MFMA_BF16(af0[i], bfr[j2][0], acc[i][j2], 0, 0, 0);
        __builtin_amdgcn_s_setprio(0);
        SBAR();

#pragma unroll
        for (int i = 0; i < 4; i++) af1[i] = *(const bf16x8*)&Ab[aoffs[i + 4][0]];
        if (j + 2 < NT) STAGE_B(j + 2, 0);
        SBAR();
        WAIT_LGKM0();
        SCHED0();
        __builtin_amdgcn_s_setprio(1);
#pragma unroll
        for (int i = 0; i < 4; i++)
#pragma unroll
            for (int j2 = 0; j2 < 4; j2++)
                acc[4 + i][j2] = MFMA_BF16(af1[i], bfr[j2][0], acc[4 + i][j2], 0, 0, 0);
        __builtin_amdgcn_s_setprio(0);
        SBAR();

#pragma unroll
        for (int i = 0; i < 4; i++) af0[i] = *(const bf16x8*)&Ab[aoffs[i][1]];
#pragma unroll
        for (int i = 0; i < 4; i++) af1[i] = *(const bf16x8*)&Ab[aoffs[i + 4][1]];
        if (j + 2 < NT) STAGE_B(j + 2, 1);
        SBAR();
        WAIT_LGKM0();
        SCHED0();
        __builtin_amdgcn_s_setprio(1);
#pragma unroll
        for (int i = 0; i < 4; i++)
#pragma unroll
            for (int j2 = 0; j2 < 4; j2++)
                acc[i][j2] = MFMA_BF16(af0[i], bfr[j2][1], acc[i][j2], 0, 0, 0);
        __builtin_amdgcn_s_setprio(0);
        SBAR();

        if (j + 2 < NT) STAGE_A(j + 2, 0);
        SBAR();
        __builtin_amdgcn_s_setprio(1);
#pragma unroll
        for (int i = 0; i < 4; i++)
#pragma unroll
            for (int j2 = 0; j2 < 4; j2++)
                acc[4 + i][j2] = MFMA_BF16(af1[i], bfr[j2][1], acc[4 + i][j2], 0, 0, 0);
        __builtin_amdgcn_s_setprio(0);
        if (j < NT - 2) WAIT_VM6(); else WAIT_VM0();
        SBAR();
    }
#undef STAGE_A
#undef STAGE_B

    const int seg    = tile_n >> 10;
    const int tn_loc = tile_n & 1023;
    bf16_t* Cout = (seg == 0) ? C0 : (seg == 1) ? C1 : C2;

    float biasf[4];
    float lbv[4][8];
#pragma unroll
    for (int j2 = 0; j2 < 4; j2++) {
        int col = tile_n + wn + j2 * 16 + c;
        biasf[j2] = bias[col];
        f32x4 lb0 = *(const f32x4*)&LB[(size_t)col * 8];
        f32x4 lb1 = *(const f32x4*)&LB[(size_t)col * 8 + 4];
#pragma unroll
        for (int r = 0; r < 4; r++) { lbv[j2][r] = lb0[r]; lbv[j2][r + 4] = lb1[r]; }
    }
#pragma unroll
    for (int i = 0; i < 8; i++) {
#pragma unroll
        for (int rg = 0; rg < 4; rg++) {
            int row = tile_m + wm + i * 16 + g * 4 + rg;
            f32x4 xa0 = *(const f32x4*)&xA[(size_t)row * 8];
            f32x4 xa1 = *(const f32x4*)&xA[(size_t)row * 8 + 4];
#pragma unroll
            for (int j2 = 0; j2 < 4; j2++) {
                float lora = xa0[0] * lbv[j2][0] + xa0[1] * lbv[j2][1] +
                             xa0[2] * lbv[j2][2] + xa0[3] * lbv[j2][3] +
                             xa1[0] * lbv[j2][4] + xa1[1] * lbv[j2][5] +
                             xa1[2] * lbv[j2][6] + xa1[3] * lbv[j2][7];
                float v = acc[i][j2][rg] + biasf[j2] + 2.0f * lora;
                int lcol = tn_loc + wn + j2 * 16 + c;
                if (Cf) Cf[(size_t)row * 1024 + lcol] = v;
                else    Cout[(size_t)row * 1024 + lcol] = (bf16_t)v;
            }
        }
    }
}

// ---------------------------------------------------------------------------
// Causal flash attention, QBLK=128 two-strip form (round-4, verified)
// + FUSED second-stage LoRA: xa2[row][r] += O[row, head-cols] . Aproj[r]
// accumulated via device-scope atomicAdd (xa2 pre-zeroed by prep_kernel).
// ---------------------------------------------------------------------------
#define VT_IDX(d, kv) ((d) * 72 + ((d) >> 4) * 8 + (kv))
#define PS_IDX(q, kv) ((q) * 72 + ((q) >> 2) * 8 + (kv))
#define PW_REGION 1168

__global__ __launch_bounds__(256, 2) void attn_kernel(
    bf16_t* __restrict__ Q, const bf16_t* __restrict__ Kg,
    const bf16_t* __restrict__ Vg,
    const float* __restrict__ Ap, float* __restrict__ xa2)
{
    __shared__ __align__(16) bf16_t Ks[64 * 72];
    __shared__ __align__(16) bf16_t Vt[64 * 72 + 32];
    __shared__ __align__(16) bf16_t Ps[8 * PW_REGION];

    const int t    = threadIdx.x;
    const int lane = t & 63;
    const int w    = t >> 6;
    const int c    = lane & 15;
    const int g    = lane >> 4;

    const int id = blockIdx.x;
    const int qb = 15 - (id >> 6);
    const int h  = id & 15;
    const int b  = (id >> 4) & 3;
    const int q0 = qb * 128;
    const size_t base = (size_t)b * 2048 * 1024;
    const int last = 2 * qb + 1;

    bf16x8 qfA[2], qfB[2];
    {
        const bf16_t* qpA = Q + base + (size_t)(q0 + w * 16 + c) * 1024 + h * 64;
        qfA[0] = *(const bf16x8*)&qpA[g * 8];
        qfA[1] = *(const bf16x8*)&qpA[32 + g * 8];
        const bf16_t* qpB = qpA + (size_t)64 * 1024;
        qfB[0] = *(const bf16x8*)&qpB[g * 8];
        qfB[1] = *(const bf16x8*)&qpB[32 + g * 8];
    }

    bf16x8 ones;
#pragma unroll
    for (int e = 0; e < 8; e++) ones[e] = (bf16_t)1.0f;

    f32x4 accA[4], accB[4];
#pragma unroll
    for (int jd = 0; jd < 4; jd++) {
        f32x4 z = {0.f, 0.f, 0.f, 0.f};
        accA[jd] = z; accB[jd] = z;
    }
    f32x4 lA = {0.f, 0.f, 0.f, 0.f};
    f32x4 lB = {0.f, 0.f, 0.f, 0.f};
    float mA = NEG_BIG, mB = NEG_BIG;

    const int sr = t >> 2;
    const int sc = (t & 3) * 16;
    const int vtbase = VT_IDX(sc, sr);

    bf16x8 kr0, kr1, vr0, vr1;
    {
        const bf16_t* kp = Kg + base + (size_t)sr * 1024 + h * 64 + sc;
        kr0 = *(const bf16x8*)&kp[0];
        kr1 = *(const bf16x8*)&kp[8];
        const bf16_t* vp = Vg + base + (size_t)sr * 1024 + h * 64 + sc;
        vr0 = *(const bf16x8*)&vp[0];
        vr1 = *(const bf16x8*)&vp[8];
    }

    bf16_t* PwA = &Ps[(w * 2 + 0) * PW_REGION];
    bf16_t* PwB = &Ps[(w * 2 + 1) * PW_REGION];
    const float SCL = 0.125f * 1.44269504088896f;

    for (int kt = 0; kt <= last; kt++) {
        if (kt > 0) __syncthreads();
        *(bf16x8*)&Ks[sr * 72 + sc]     = kr0;
        *(bf16x8*)&Ks[sr * 72 + sc + 8] = kr1;
#pragma unroll
        for (int e = 0; e < 8; e++) Vt[vtbase + e * 72]       = vr0[e];
#pragma unroll
        for (int e = 0; e < 8; e++) Vt[vtbase + (e + 8) * 72] = vr1[e];
        __syncthreads();

        if (kt < last) {
            const bf16_t* kp = Kg + base + (size_t)((kt + 1) * 64 + sr) * 1024 + h * 64 + sc;
            kr0 = *(const bf16x8*)&kp[0];
            kr1 = *(const bf16x8*)&kp[8];
            const bf16_t* vp = Vg + base + (size_t)((kt + 1) * 64 + sr) * 1024 + h * 64 + sc;
            vr0 = *(const bf16x8*)&vp[0];
            vr1 = *(const bf16x8*)&vp[8];
        }

        const bool doA = (kt <= 2 * qb);

        f32x4 sA[4], sB[4];
#pragma unroll
        for (int j = 0; j < 4; j++) {
            f32x4 z = {0.f, 0.f, 0.f, 0.f};
            sA[j] = z; sB[j] = z;
        }
#pragma unroll
        for (int kk = 0; kk < 2; kk++) {
            bf16x8 kf[4];
#pragma unroll
            for (int j = 0; j < 4; j++)
                kf[j] = *(const bf16x8*)&Ks[(j * 16 + c) * 72 + kk * 32 + g * 8];
            if (doA) {
#pragma unroll
                for (int j = 0; j < 4; j++)
                    sA[j] = MFMA_BF16(kf[j], qfA[kk], sA[j], 0, 0, 0);
            }
#pragma unroll
            for (int j = 0; j < 4; j++)
                sB[j] = MFMA_BF16(kf[j], qfB[kk], sB[j], 0, 0, 0);
        }

        if (doA) {
#pragma unroll
            for (int j = 0; j < 4; j++)
#pragma unroll
                for (int r = 0; r < 4; r++) sA[j][r] *= SCL;
            if (kt == 2 * qb) {
#pragma unroll
                for (int j = 0; j < 4; j++)
#pragma unroll
                    for (int r = 0; r < 4; r++)
                        if (j * 16 + g * 4 + r > w * 16 + c) sA[j][r] = NEG_BIG;
            }
            float mx;
            {
                float a0 = fmaxf(fmaxf(sA[0][0], sA[0][1]), fmaxf(sA[0][2], sA[0][3]));
                float a1 = fmaxf(fmaxf(sA[1][0], sA[1][1]), fmaxf(sA[1][2], sA[1][3]));
                float a2 = fmaxf(fmaxf(sA[2][0], sA[2][1]), fmaxf(sA[2][2], sA[2][3]));
                float a3 = fmaxf(fmaxf(sA[3][0], sA[3][1]), fmaxf(sA[3][2], sA[3][3]));
                mx = fmaxf(fmaxf(a0, a1), fmaxf(a2, a3));
                mx = fmaxf(mx, __shfl_xor(mx, 16));
                mx = fmaxf(mx, __shfl_xor(mx, 32));
            }
            if (!__all(mx <= mA + 8.0f)) {
                float mnew  = fmaxf(mA, mx);
                float alpha = EXP2F(mA - mnew);
                mA = mnew;
#pragma unroll
                for (int jd = 0; jd < 4; jd++)
#pragma unroll
                    for (int r = 0; r < 4; r++) accA[jd][r] *= alpha;
                lA[0] *= alpha;
            }
#pragma unroll
            for (int j = 0; j < 4; j++)
#pragma unroll
                for (int r = 0; r < 4; r++) sA[j][r] = EXP2F(sA[j][r] - mA);
#pragma unroll
            for (int j = 0; j < 4; j++) {
                bf16x4 pk;
#pragma unroll
                for (int r = 0; r < 4; r++) pk[r] = (bf16_t)sA[j][r];
                *(bf16x4*)&PwA[PS_IDX(c, j * 16 + g * 4)] = pk;
            }
        }

        {
#pragma unroll
            for (int j = 0; j < 4; j++)
#pragma unroll
                for (int r = 0; r < 4; r++) sB[j][r] *= SCL;
            if (kt == last) {
#pragma unroll
                for (int j = 0; j < 4; j++)
#pragma unroll
                    for (int r = 0; r < 4; r++)
                        if (j * 16 + g * 4 + r > w * 16 + c) sB[j][r] = NEG_BIG;
            }
            float mx;
            {
                float a0 = fmaxf(fmaxf(sB[0][0], sB[0][1]), fmaxf(sB[0][2], sB[0][3]));
                float a1 = fmaxf(fmaxf(sB[1][0], sB[1][1]), fmaxf(sB[1][2], sB[1][3]));
                float a2 = fmaxf(fmaxf(sB[2][0], sB[2][1]), fmaxf(sB[2][2], sB[2][3]));
                float a3 = fmaxf(fmaxf(sB[3][0], sB[3][1]), fmaxf(sB[3][2], sB[3][3]));
                mx = fmaxf(fmaxf(a0, a1), fmaxf(a2, a3));
                mx = fmaxf(mx, __shfl_xor(mx, 16));
                mx = fmaxf(mx, __shfl_xor(mx, 32));
            }
            if (!__all(mx <= mB + 8.0f)) {
                float mnew  = fmaxf(mB, mx);
                float alpha = EXP2F(mB - mnew);
                mB = mnew;
#pragma unroll
                for (int jd = 0; jd < 4; jd++)
#pragma unroll
                    for (int r = 0; r < 4; r++) accB[jd][r] *= alpha;
                lB[0] *= alpha;
            }
#pragma unroll
            for (int j = 0; j < 4; j++)
#pragma unroll
                for (int r = 0; r < 4; r++) sB[j][r] = EXP2F(sB[j][r] - mB);
#pragma unroll
            for (int j = 0; j < 4; j++) {
                bf16x4 pk;
#pragma unroll
                for (int r = 0; r < 4; r++) pk[r] = (bf16_t)sB[j][r];
                *(bf16x4*)&PwB[PS_IDX(c, j * 16 + g * 4)] = pk;
            }
        }

#pragma unroll
        for (int kkv = 0; kkv < 2; kkv++) {
            bf16x8 vf[4];
#pragma unroll
            for (int jd = 0; jd < 4; jd++)
                vf[jd] = *(const bf16x8*)&Vt[VT_IDX(jd * 16 + c, kkv * 32 + g * 8)];
            if (doA) {
                bf16x8 pfA = *(const bf16x8*)&PwA[PS_IDX(c, kkv * 32 + g * 8)];
#pragma unroll
                for (int jd = 0; jd < 4; jd++)
                    accA[jd] = MFMA_BF16(vf[jd], pfA, accA[jd], 0, 0, 0);
                lA = MFMA_BF16(ones, pfA, lA, 0, 0, 0);
            }
            bf16x8 pfB = *(const bf16x8*)&PwB[PS_IDX(c, kkv * 32 + g * 8)];
#pragma unroll
            for (int jd = 0; jd < 4; jd++)
                accB[jd] = MFMA_BF16(vf[jd], pfB, accB[jd], 0, 0, 0);
            lB = MFMA_BF16(ones, pfB, lB, 0, 0, 0);
        }
    }

    // ---- epilogue: store O (packed 8B) + fused xa2 accumulation ----
    const float* Ah = Ap ? (Ap + h * 64 + g * 4) : nullptr;
    {
        float rl = 1.0f / lA[0];
        int qrow = q0 + w * 16 + c;
        bf16_t* op = Q + base + (size_t)qrow * 1024 + h * 64;
        float ov[4][4];
#pragma unroll
        for (int jd = 0; jd < 4; jd++) {
            bf16x4 o4;
#pragma unroll
            for (int r = 0; r < 4; r++) {
                ov[jd][r] = accA[jd][r] * rl;
                o4[r] = (bf16_t)ov[jd][r];
            }
            *(bf16x4*)&op[jd * 16 + g * 4] = o4;
        }
        if (xa2) {
            size_t rowg = base / 1024 + qrow;
#pragma unroll
            for (int r8 = 0; r8 < 8; r8++) {
                float s = 0.f;
#pragma unroll
                for (int jd = 0; jd < 4; jd++) {
                    f32x4 a = *(const f32x4*)&Ah[(size_t)r8 * 1024 + jd * 16];
                    s += ov[jd][0] * a[0] + ov[jd][1] * a[1] +
                         ov[jd][2] * a[2] + ov[jd][3] * a[3];
                }
                s += __shfl_xor(s, 16);
                s += __shfl_xor(s, 32);
                if (g == 0) atomicAdd(&xa2[rowg * 8 + r8], s);
            }
        }
    }
    {
        float rl = 1.0f / lB[0];
        int qrow = q0 + 64 + w * 16 + c;
        bf16_t* op = Q + base + (size_t)qrow * 1024 + h * 64;
        float ov[4][4];
#pragma unroll
        for (int jd = 0; jd < 4; jd++) {
            bf16x4 o4;
#pragma unroll
            for (int r = 0; r < 4; r++) {
                ov[jd][r] = accB[jd][r] * rl;
                o4[r] = (bf16_t)ov[jd][r];
            }
            *(bf16x4*)&op[jd * 16 + g * 4] = o4;
        }
        if (xa2) {
            size_t rowg = base / 1024 + qrow;
#pragma unroll
            for (int r8 = 0; r8 < 8; r8++) {
                float s = 0.f;
#pragma unroll
                for (int jd = 0; jd < 4; jd++) {
                    f32x4 a = *(const f32x4*)&Ah[(size_t)r8 * 1024 + jd * 16];
                    s += ov[jd][0] * a[0] + ov[jd][1] * a[1] +
                         ov[jd][2] * a[2] + ov[jd][3] * a[3];
                }
                s += __shfl_xor(s, 16);
                s += __shfl_xor(s, 32);
                if (g == 0) atomicAdd(&xa2[rowg * 8 + r8], s);
            }
        }
    }
}

// ---------------------------------------------------------------------------
extern "C" void kernel_launch(void* const* d_in, const int* in_sizes, int n_in,
                              void* d_out, int out_size, void* d_ws, size_t ws_size,
                              hipStream_t stream) {
    const float* x     = (const float*)d_in[0];
    const float* Wqkv  = (const float*)d_in[1];
    const float* bqkv  = (const float*)d_in[2];
    const float* Aqkv  = (const float*)d_in[3];
    const float* Bqkv  = (const float*)d_in[4];
    const float* Wproj = (const float*)d_in[5];
    const float* bproj = (const float*)d_in[6];
    const float* Aproj = (const float*)d_in[7];
    const float* Bproj = (const float*)d_in[8];
    float* out = (float*)d_out;

    char* ws = (char*)d_ws;
    const bool big = ws_size >= (size_t)(72.5 * 1024 * 1024) + 65536;

    if (big) {
        float*  xa1    = (float*)ws;
        float*  xa2    = (float*)(ws + 262144);
        bf16_t* x16    = (bf16_t*)(ws + 524288);
        bf16_t* Wqkv16 = x16 + (size_t)8192 * 1024;
        bf16_t* Wproj16= Wqkv16 + (size_t)3072 * 1024;
        bf16_t* Qfull  = Wproj16 + (size_t)1024 * 1024;
        bf16_t* Kfull  = Qfull + (size_t)8192 * 1024;
        bf16_t* Vfull  = Kfull + (size_t)8192 * 1024;

        // converts + xa1 + zero(xa2)
        prep_kernel<<<8200, 256, 0, stream>>>(
            x, Wqkv, Wproj, x16, Wqkv16, Wproj16, Aqkv, xa1, xa2);

        gemm_256<<<384, 512, 0, stream>>>(
            x16, Wqkv16, bqkv, xa1, Bqkv, Qfull, Kfull, Vfull, nullptr, 1024, 12);

        // attn + fused second-stage LoRA (xa2 accumulation)
        attn_kernel<<<1024, 256, 0, stream>>>(Qfull, Kfull, Vfull, Aproj, xa2);

        gemm_async<<<dim3(8, 64), 256, 0, stream>>>(
            Qfull, Wproj16, bproj, xa2, Bproj,
            nullptr, nullptr, nullptr, out, 1024);
    } else {
        float*  xa1   = (float*)ws;
        float*  xa2   = (float*)(ws + 262144);
        bf16_t* Qfull = (bf16_t*)(ws + 524288);
        bf16_t* Kfull = Qfull + (size_t)8192 * 1024;
        bf16_t* Vfull = Kfull + (size_t)8192 * 1024;

        lora_xa_kernel<float><<<2048, 256, 0, stream>>>(x, Aqkv, xa1);
        gemm_bias_lora<float, float><<<dim3(24, 64), 256, 0, stream>>>(
            x, Wqkv, bqkv, xa1, Bqkv, Qfull, Kfull, Vfull, nullptr, 1024);
        attn_kernel<<<1024, 256, 0, stream>>>(Qfull, Kfull, Vfull, nullptr, nullptr);
        lora_xa_kernel<bf16_t><<<2048, 256, 0, stream>>>(Qfull, Aproj, xa2);
        gemm_bias_lora<bf16_t, float><<<dim3(8, 64), 256, 0, stream>>>(
            Qfull, Wproj, bproj, xa2, Bproj,
            nullptr, nullptr, nullptr, out, 1024);
    }
}

// Round 7
// 315.917 us; speedup vs baseline: 1.0807x; 1.0807x over previous
//
#include <hip/hip_runtime.h>
#include <hip/hip_bf16.h>

typedef __bf16 bf16_t;
typedef __bf16 bf16x8 __attribute__((ext_vector_type(8)));
typedef __bf16 bf16x4 __attribute__((ext_vector_type(4)));
typedef float  f32x4  __attribute__((ext_vector_type(4)));

#define MFMA_BF16 __builtin_amdgcn_mfma_f32_16x16x32_bf16
#define NEG_BIG  (-3.0e38f)

#if __has_builtin(__builtin_amdgcn_exp2f)
#define EXP2F(x) __builtin_amdgcn_exp2f(x)
#else
#define EXP2F(x) exp2f(x)
#endif

#define SBAR()       __builtin_amdgcn_s_barrier()
#define SCHED0()     __builtin_amdgcn_sched_barrier(0)
#define WAIT_LGKM0() asm volatile("s_waitcnt lgkmcnt(0)" ::: "memory")
#define WAIT_LGKM8() asm volatile("s_waitcnt lgkmcnt(8)" ::: "memory")
#define WAIT_VM0()   asm volatile("s_waitcnt vmcnt(0)" ::: "memory")
#define WAIT_VM4()   asm volatile("s_waitcnt vmcnt(4)" ::: "memory")
#define WAIT_VM6()   asm volatile("s_waitcnt vmcnt(6)" ::: "memory")

// async global->LDS 16B copy (gfx950 dwordx4 variant)
__device__ __forceinline__ void load16_lds(const bf16_t* g, bf16_t* l) {
    __builtin_amdgcn_global_load_lds(
        (const __attribute__((address_space(1))) void*)g,
        (__attribute__((address_space(3))) void*)l, 16, 0, 0);
}

// load 8 contiguous elements as bf16x8, converting if source is fp32
__device__ inline bf16x8 ld8(const bf16_t* p) { return *(const bf16x8*)p; }
__device__ inline bf16x8 ld8(const float* p) {
    f32x4 a = *(const f32x4*)p;
    f32x4 b = *(const f32x4*)(p + 4);
    bf16x8 o;
    o[0] = (bf16_t)a[0]; o[1] = (bf16_t)a[1]; o[2] = (bf16_t)a[2]; o[3] = (bf16_t)a[3];
    o[4] = (bf16_t)b[0]; o[5] = (bf16_t)b[1]; o[6] = (bf16_t)b[2]; o[7] = (bf16_t)b[3];
    return o;
}

// ---------------------------------------------------------------------------
// LoRA first stage body: out[m][r] = sum_k X[m][k] * A[r][k]
// ---------------------------------------------------------------------------
template <typename TX>
__device__ __forceinline__ void lora_xa_body(
    const TX* __restrict__ X, const float* __restrict__ A,
    float* __restrict__ out, int m, int lane)
{
    const TX* xp = X + (size_t)m * 1024;
    float acc[8];
#pragma unroll
    for (int r = 0; r < 8; r++) acc[r] = 0.f;

#pragma unroll 4
    for (int ci = 0; ci < 16; ci++) {
        int k = ci * 64 + lane;
        float xv = (float)xp[k];
#pragma unroll
        for (int r = 0; r < 8; r++) acc[r] += xv * A[r * 1024 + k];
    }
#pragma unroll
    for (int r = 0; r < 8; r++) {
        float v = acc[r];
        v += __shfl_xor(v, 1);  v += __shfl_xor(v, 2);  v += __shfl_xor(v, 4);
        v += __shfl_xor(v, 8);  v += __shfl_xor(v, 16); v += __shfl_xor(v, 32);
        if (lane == 0) out[m * 8 + r] = v;
    }
}

template <typename TX>
__global__ __launch_bounds__(256) void lora_xa_kernel(
    const TX* __restrict__ X, const float* __restrict__ A,
    float* __restrict__ out)
{
    const int lane = threadIdx.x & 63;
    const int w    = threadIdx.x >> 6;
    const int m    = blockIdx.x * 4 + w;
    lora_xa_body<TX>(X, A, out, m, lane);
}

// ---------------------------------------------------------------------------
// Fused prep: fp32->bf16 converts for x / Wqkv / Wproj + first-stage LoRA
// ---------------------------------------------------------------------------
__global__ __launch_bounds__(256) void prep_kernel(
    const float* __restrict__ x, const float* __restrict__ Wqkv,
    const float* __restrict__ Wproj,
    bf16_t* __restrict__ x16, bf16_t* __restrict__ Wqkv16,
    bf16_t* __restrict__ Wproj16,
    const float* __restrict__ Aqkv, float* __restrict__ xa1)
{
    const int bid = blockIdx.x;
    if (bid < 6144) {
        const float* in; bf16_t* out; size_t off;
        if (bid < 4096)      { in = x;     out = x16;     off = (size_t)bid * 2048; }
        else if (bid < 5632) { in = Wqkv;  out = Wqkv16;  off = (size_t)(bid - 4096) * 2048; }
        else                 { in = Wproj; out = Wproj16; off = (size_t)(bid - 5632) * 2048; }
        size_t i = off + (size_t)threadIdx.x * 8;
        *(bf16x8*)&out[i] = ld8(&in[i]);
    } else {
        const int lane = threadIdx.x & 63;
        const int w    = threadIdx.x >> 6;
        const int m    = (bid - 6144) * 4 + w;
        lora_xa_body<float>(x, Aqkv, xa1, m, lane);
    }
}

// ---------------------------------------------------------------------------
// Shared epilogue for 4x4 acc (128-tile kernels)
// ---------------------------------------------------------------------------
__device__ __forceinline__ void gemm_epilogue(
    f32x4 (&acc)[4][4], const float* bias, const float* xA, const float* LB,
    bf16_t* C0, bf16_t* C1, bf16_t* C2, float* Cf,
    int tile_m, int tile_n, int wm, int wn, int c, int g)
{
    const int seg    = tile_n >> 10;
    const int tn_loc = tile_n & 1023;
    bf16_t* Cout = (seg == 0) ? C0 : (seg == 1) ? C1 : C2;

    float biasf[4];
    float lbv[4][8];
#pragma unroll
    for (int j = 0; j < 4; j++) {
        int col = tile_n + wn + j * 16 + c;
        biasf[j] = bias[col];
        f32x4 lb0 = *(const f32x4*)&LB[(size_t)col * 8];
        f32x4 lb1 = *(const f32x4*)&LB[(size_t)col * 8 + 4];
#pragma unroll
        for (int r = 0; r < 4; r++) { lbv[j][r] = lb0[r]; lbv[j][r + 4] = lb1[r]; }
    }
#pragma unroll
    for (int i = 0; i < 4; i++) {
#pragma unroll
        for (int rg = 0; rg < 4; rg++) {
            int row = tile_m + wm + i * 16 + g * 4 + rg;
            f32x4 xa0 = *(const f32x4*)&xA[(size_t)row * 8];
            f32x4 xa1 = *(const f32x4*)&xA[(size_t)row * 8 + 4];
#pragma unroll
            for (int j = 0; j < 4; j++) {
                float lora = xa0[0] * lbv[j][0] + xa0[1] * lbv[j][1] +
                             xa0[2] * lbv[j][2] + xa0[3] * lbv[j][3] +
                             xa1[0] * lbv[j][4] + xa1[1] * lbv[j][5] +
                             xa1[2] * lbv[j][6] + xa1[3] * lbv[j][7];
                float v = acc[i][j][rg] + biasf[j] + 2.0f * lora;
                int lcol = tn_loc + wn + j * 16 + c;
                if (Cf) Cf[(size_t)row * 1024 + lcol] = v;
                else    Cout[(size_t)row * 1024 + lcol] = (bf16_t)v;
            }
        }
    }
}

// ---------------------------------------------------------------------------
// FALLBACK GEMM (small-ws path): VGPR staging, inline fp32->bf16 cvt.
// ---------------------------------------------------------------------------
template <typename TA, typename TW>
__global__ __launch_bounds__(256) void gemm_bias_lora(
    const TA* __restrict__ A, const TW* __restrict__ W,
    const float* __restrict__ bias, const float* __restrict__ xA,
    const float* __restrict__ LB,
    bf16_t* __restrict__ C0, bf16_t* __restrict__ C1, bf16_t* __restrict__ C2,
    float* __restrict__ Cf, int K)
{
    __shared__ __align__(16) bf16_t As[128 * 72];
    __shared__ __align__(16) bf16_t Bs[128 * 72];

    const int t    = threadIdx.x;
    const int lane = t & 63;
    const int w    = t >> 6;
    const int wm   = (w >> 1) * 64;
    const int wn   = (w & 1) * 64;
    const int c    = lane & 15;
    const int g    = lane >> 4;
    const int tile_m = blockIdx.y * 128;
    const int tile_n = blockIdx.x * 128;

    const int srow = t >> 3;
    const int scol = (t & 7) * 8;

    f32x4 acc[4][4];
#pragma unroll
    for (int i = 0; i < 4; i++)
#pragma unroll
        for (int j = 0; j < 4; j++) {
            f32x4 z = {0.f, 0.f, 0.f, 0.f};
            acc[i][j] = z;
        }

    for (int k0 = 0; k0 < K; k0 += 64) {
#pragma unroll
        for (int i = 0; i < 4; i++) {
            int r = srow + i * 32;
            *(bf16x8*)&As[r * 72 + scol] = ld8(&A[(size_t)(tile_m + r) * K + k0 + scol]);
            *(bf16x8*)&Bs[r * 72 + scol] = ld8(&W[(size_t)(tile_n + r) * K + k0 + scol]);
        }
        __syncthreads();

#pragma unroll
        for (int kk = 0; kk < 2; kk++) {
            bf16x8 af[4], bfr[4];
#pragma unroll
            for (int i = 0; i < 4; i++)
                af[i] = *(const bf16x8*)&As[(wm + i * 16 + c) * 72 + kk * 32 + g * 8];
#pragma unroll
            for (int j = 0; j < 4; j++)
                bfr[j] = *(const bf16x8*)&Bs[(wn + j * 16 + c) * 72 + kk * 32 + g * 8];
#pragma unroll
            for (int i = 0; i < 4; i++)
#pragma unroll
                for (int j = 0; j < 4; j++)
                    acc[i][j] = MFMA_BF16(af[i], bfr[j], acc[i][j], 0, 0, 0);
        }
        __syncthreads();
    }
    gemm_epilogue(acc, bias, xA, LB, C0, C1, C2, Cf, tile_m, tile_n, wm, wn, c, g);
}

// ---------------------------------------------------------------------------
// ASYNC GEMM 128x128 (m97 structure) — proj GEMM.  Round-4 proven version.
// ---------------------------------------------------------------------------
#define AS_OFF(row, q) ((row) * 64 + (((q) ^ ((row) & 7)) * 8))

__global__ __launch_bounds__(256) void gemm_async(
    const bf16_t* __restrict__ A, const bf16_t* __restrict__ W,
    const float* __restrict__ bias, const float* __restrict__ xA,
    const float* __restrict__ LB,
    bf16_t* __restrict__ C0, bf16_t* __restrict__ C1, bf16_t* __restrict__ C2,
    float* __restrict__ Cf, int K)
{
    __shared__ __align__(16) bf16_t As[128 * 64];
    __shared__ __align__(16) bf16_t Bs[128 * 64];

    const int t    = threadIdx.x;
    const int lane = t & 63;
    const int w    = t >> 6;
    const int wm   = (w >> 1) * 64;
    const int wn   = (w & 1) * 64;
    const int c    = lane & 15;
    const int g    = lane >> 4;
    const int tile_m = blockIdx.y * 128;
    const int tile_n = blockIdx.x * 128;

    const int trow = t >> 3;                   // 0..31
    const int k8   = (t & 7) ^ (trow & 7);     // swizzled k-chunk for staging
    const bf16_t* Ab = A + (size_t)tile_m * K + k8 * 8;
    const bf16_t* Wb = W + (size_t)tile_n * K + k8 * 8;

    f32x4 acc[4][4];
#pragma unroll
    for (int i = 0; i < 4; i++)
#pragma unroll
        for (int j = 0; j < 4; j++) {
            f32x4 z = {0.f, 0.f, 0.f, 0.f};
            acc[i][j] = z;
        }

    for (int k0 = 0; k0 < K; k0 += 64) {
#pragma unroll
        for (int i = 0; i < 4; i++) {
            int row = i * 32 + trow;
            load16_lds(&Ab[(size_t)row * K + k0], &As[(i * 256 + t) * 8]);
            load16_lds(&Wb[(size_t)row * K + k0], &Bs[(i * 256 + t) * 8]);
        }
        __syncthreads();

#pragma unroll
        for (int kk = 0; kk < 2; kk++) {
            bf16x8 af[4], bfr[4];
#pragma unroll
            for (int i = 0; i < 4; i++)
                af[i] = *(const bf16x8*)&As[AS_OFF(wm + i * 16 + c, kk * 4 + g)];
#pragma unroll
            for (int j = 0; j < 4; j++)
                bfr[j] = *(const bf16x8*)&Bs[AS_OFF(wn + j * 16 + c, kk * 4 + g)];
#pragma unroll
            for (int i = 0; i < 4; i++)
#pragma unroll
                for (int j = 0; j < 4; j++)
                    acc[i][j] = MFMA_BF16(af[i], bfr[j], acc[i][j], 0, 0, 0);
        }
        __syncthreads();
    }
    gemm_epilogue(acc, bias, xA, LB, C0, C1, C2, Cf, tile_m, tile_n, wm, wn, c, g);
}

// ---------------------------------------------------------------------------
// 256x256 GEMM — round-4 proven version (unswapped, inline old epilogue).
// ---------------------------------------------------------------------------
__global__ __launch_bounds__(512, 2) void gemm_256(
    const bf16_t* __restrict__ A, const bf16_t* __restrict__ W,
    const float* __restrict__ bias, const float* __restrict__ xA,
    const float* __restrict__ LB,
    bf16_t* __restrict__ C0, bf16_t* __restrict__ C1, bf16_t* __restrict__ C2,
    float* __restrict__ Cf, int K, int ntn)
{
    __shared__ __align__(16) bf16_t As[4][8192];   // [buf*2+half][128*64]
    __shared__ __align__(16) bf16_t Bs[4][8192];

    const int t    = threadIdx.x;
    const int lane = t & 63;
    const int w    = t >> 6;
    const int c    = lane & 15;
    const int g    = lane >> 4;

    const int nwg = gridDim.x;
    const int cpx = nwg >> 3;
    const int bid = blockIdx.x;
    const int swz = (bid & 7) * cpx + (bid >> 3);
    const int tile_m = (swz / ntn) * 256;
    const int tile_n = (swz % ntn) * 256;

    const int wm  = (w >> 2) * 128;
    const int wn  = (w & 3) * 64;
    const int ha  = w >> 2;
    const int hb  = wn >> 7;
    const int wnl = wn & 127;

    int aoffs[8][2], boffs[4][2];
#pragma unroll
    for (int il = 0; il < 8; il++) {
        int rl = il * 16 + c;
#pragma unroll
        for (int ks = 0; ks < 2; ks++)
            aoffs[il][ks] = rl * 64 + (((ks * 4 + g) ^ (rl & 7)) * 8);
    }
#pragma unroll
    for (int j2 = 0; j2 < 4; j2++) {
        int rl = wnl + j2 * 16 + c;
#pragma unroll
        for (int ks = 0; ks < 2; ks++)
            boffs[j2][ks] = rl * 64 + (((ks * 4 + g) ^ (rl & 7)) * 8);
    }

    const int trow = t >> 3;
    const int qq   = (t & 7) ^ (trow & 7);
    const bf16_t* aO = A + (size_t)(tile_m + trow) * K + qq * 8;
    const bf16_t* wO = W + (size_t)(tile_n + trow) * K + qq * 8;
    const size_t rK64 = (size_t)64 * K;

#define STAGE_A(T, h) do {                                                         \
    load16_lds(aO + (size_t)(h) * 128 * K + (size_t)(T) * 64,                      \
               &As[((T) & 1) * 2 + (h)][t * 8]);                                   \
    load16_lds(aO + (size_t)(h) * 128 * K + rK64 + (size_t)(T) * 64,               \
               &As[((T) & 1) * 2 + (h)][4096 + t * 8]); } while (0)
#define STAGE_B(T, h) do {                                                         \
    load16_lds(wO + (size_t)(h) * 128 * K + (size_t)(T) * 64,                      \
               &Bs[((T) & 1) * 2 + (h)][t * 8]);                                   \
    load16_lds(wO + (size_t)(h) * 128 * K + rK64 + (size_t)(T) * 64,               \
               &Bs[((T) & 1) * 2 + (h)][4096 + t * 8]); } while (0)

    f32x4 acc[8][4];
#pragma unroll
    for (int i = 0; i < 8; i++)
#pragma unroll
        for (int j2 = 0; j2 < 4; j2++) {
            f32x4 z = {0.f, 0.f, 0.f, 0.f};
            acc[i][j2] = z;
        }

    const int NT = K >> 6;

    STAGE_B(0, 0); STAGE_B(0, 1); STAGE_A(0, 0); STAGE_A(0, 1);
    WAIT_VM4();
    STAGE_B(1, 0); STAGE_B(1, 1); STAGE_A(1, 0);
    WAIT_VM6();
    SBAR();

    for (int j = 0; j < NT; j++) {
        const bf16_t* Ab = &As[(j & 1) * 2 + ha][0];
        const bf16_t* Bb = &Bs[(j & 1) * 2 + hb][0];
        bf16x8 bfr[4][2], af0[4], af1[4];

#pragma unroll
        for (int j2 = 0; j2 < 4; j2++) {
            bfr[j2][0] = *(const bf16x8*)&Bb[boffs[j2][0]];
            bfr[j2][1] = *(const bf16x8*)&Bb[boffs[j2][1]];
        }
#pragma unroll
        for (int i = 0; i < 4; i++) af0[i] = *(const bf16x8*)&Ab[aoffs[i][0]];
        if (j + 1 < NT) STAGE_A(j + 1, 1);
        WAIT_LGKM8();
        SBAR();
        WAIT_LGKM0();
        SCHED0();
        __builtin_amdgcn_s_setprio(1);
#pragma unroll
        for (int i = 0; i < 4; i++)
#pragma unroll
            for (int j2 = 0; j2 < 4; j2++)
                acc[i][j2] = MFMA_BF16(af0[i], bfr[j2][0], acc[i][j2], 0, 0, 0);
        __builtin_amdgcn_s_setprio(0);
        SBAR();

#pragma unroll
        for (int i = 0; i < 4; i++) af1[i] = *(const bf16x8*)&Ab[aoffs[i + 4][0]];
        if (j + 2 < NT) STAGE_B(j + 2, 0);
        SBAR();
        WAIT_LGKM0();
        SCHED0();
        __builtin_amdgcn_s_setprio(1);
#pragma unroll
        for (int i = 0; i < 4; i++)
#pragma unroll
            for (int j2 = 0; j2 < 4; j2++)
                acc[4 + i][j2] = MFMA_BF16(af1[i], bfr[j2][0], acc[4 + i][j2], 0, 0, 0);
        __builtin_amdgcn_s_setprio(0);
        SBAR();

#pragma unroll
        for (int i = 0; i < 4; i++) af0[i] = *(const bf16x8*)&Ab[aoffs[i][1]];
#pragma unroll
        for (int i = 0; i < 4; i++) af1[i] = *(const bf16x8*)&Ab[aoffs[i + 4][1]];
        if (j + 2 < NT) STAGE_B(j + 2, 1);
        SBAR();
        WAIT_LGKM0();
        SCHED0();
        __builtin_amdgcn_s_setprio(1);
#pragma unroll
        for (int i = 0; i < 4; i++)
#pragma unroll
            for (int j2 = 0; j2 < 4; j2++)
                acc[i][j2] = MFMA_BF16(af0[i], bfr[j2][1], acc[i][j2], 0, 0, 0);
        __builtin_amdgcn_s_setprio(0);
        SBAR();

        if (j + 2 < NT) STAGE_A(j + 2, 0);
        SBAR();
        __builtin_amdgcn_s_setprio(1);
#pragma unroll
        for (int i = 0; i < 4; i++)
#pragma unroll
            for (int j2 = 0; j2 < 4; j2++)
                acc[4 + i][j2] = MFMA_BF16(af1[i], bfr[j2][1], acc[4 + i][j2], 0, 0, 0);
        __builtin_amdgcn_s_setprio(0);
        if (j < NT - 2) WAIT_VM6(); else WAIT_VM0();
        SBAR();
    }
#undef STAGE_A
#undef STAGE_B

    const int seg    = tile_n >> 10;
    const int tn_loc = tile_n & 1023;
    bf16_t* Cout = (seg == 0) ? C0 : (seg == 1) ? C1 : C2;

    float biasf[4];
    float lbv[4][8];
#pragma unroll
    for (int j2 = 0; j2 < 4; j2++) {
        int col = tile_n + wn + j2 * 16 + c;
        biasf[j2] = bias[col];
        f32x4 lb0 = *(const f32x4*)&LB[(size_t)col * 8];
        f32x4 lb1 = *(const f32x4*)&LB[(size_t)col * 8 + 4];
#pragma unroll
        for (int r = 0; r < 4; r++) { lbv[j2][r] = lb0[r]; lbv[j2][r + 4] = lb1[r]; }
    }
#pragma unroll
    for (int i = 0; i < 8; i++) {
#pragma unroll
        for (int rg = 0; rg < 4; rg++) {
            int row = tile_m + wm + i * 16 + g * 4 + rg;
            f32x4 xa0 = *(const f32x4*)&xA[(size_t)row * 8];
            f32x4 xa1 = *(const f32x4*)&xA[(size_t)row * 8 + 4];
#pragma unroll
            for (int j2 = 0; j2 < 4; j2++) {
                float lora = xa0[0] * lbv[j2][0] + xa0[1] * lbv[j2][1] +
                             xa0[2] * lbv[j2][2] + xa0[3] * lbv[j2][3] +
                             xa1[0] * lbv[j2][4] + xa1[1] * lbv[j2][5] +
                             xa1[2] * lbv[j2][6] + xa1[3] * lbv[j2][7];
                float v = acc[i][j2][rg] + biasf[j2] + 2.0f * lora;
                int lcol = tn_loc + wn + j2 * 16 + c;
                if (Cf) Cf[(size_t)row * 1024 + lcol] = v;
                else    Cout[(size_t)row * 1024 + lcol] = (bf16_t)v;
            }
        }
    }
}

// ---------------------------------------------------------------------------
// Causal flash attention, QBLK=128 two-strip form (round-4, verified).
// Vt rotation changed (d>>4)*8 -> (d>>4)*16: the four sc-group transpose-
// store windows land on disjoint bank octets (starts 4e,4e+8,4e+16,4e+24)
// instead of overlapping (4e,4e+4,...).  Read pattern unchanged-ideal
// (rotation term is constant per fragment).
// ---------------------------------------------------------------------------
#define VT_IDX(d, kv) ((d) * 72 + ((d) >> 4) * 16 + (kv))
#define PS_IDX(q, kv) ((q) * 72 + ((q) >> 2) * 8 + (kv))
#define PW_REGION 1168

__global__ __launch_bounds__(256, 2) void attn_kernel(
    bf16_t* __restrict__ Q, const bf16_t* __restrict__ Kg,
    const bf16_t* __restrict__ Vg)
{
    __shared__ __align__(16) bf16_t Ks[64 * 72];
    __shared__ __align__(16) bf16_t Vt[64 * 72 + 64];
    __shared__ __align__(16) bf16_t Ps[8 * PW_REGION];

    const int t    = threadIdx.x;
    const int lane = t & 63;
    const int w    = t >> 6;
    const int c    = lane & 15;
    const int g    = lane >> 4;

    const int id = blockIdx.x;
    const int qb = 15 - (id >> 6);
    const int h  = id & 15;
    const int b  = (id >> 4) & 3;
    const int q0 = qb * 128;
    const size_t base = (size_t)b * 2048 * 1024;
    const int last = 2 * qb + 1;

    bf16x8 qfA[2], qfB[2];
    {
        const bf16_t* qpA = Q + base + (size_t)(q0 + w * 16 + c) * 1024 + h * 64;
        qfA[0] = *(const bf16x8*)&qpA[g * 8];
        qfA[1] = *(const bf16x8*)&qpA[32 + g * 8];
        const bf16_t* qpB = qpA + (size_t)64 * 1024;
        qfB[0] = *(const bf16x8*)&qpB[g * 8];
        qfB[1] = *(const bf16x8*)&qpB[32 + g * 8];
    }

    bf16x8 ones;
#pragma unroll
    for (int e = 0; e < 8; e++) ones[e] = (bf16_t)1.0f;

    f32x4 accA[4], accB[4];
#pragma unroll
    for (int jd = 0; jd < 4; jd++) {
        f32x4 z = {0.f, 0.f, 0.f, 0.f};
        accA[jd] = z; accB[jd] = z;
    }
    f32x4 lA = {0.f, 0.f, 0.f, 0.f};
    f32x4 lB = {0.f, 0.f, 0.f, 0.f};
    float mA = NEG_BIG, mB = NEG_BIG;

    const int sr = t >> 2;
    const int sc = (t & 3) * 16;
    const int vtbase = VT_IDX(sc, sr);

    bf16x8 kr0, kr1, vr0, vr1;
    {
        const bf16_t* kp = Kg + base + (size_t)sr * 1024 + h * 64 + sc;
        kr0 = *(const bf16x8*)&kp[0];
        kr1 = *(const bf16x8*)&kp[8];
        const bf16_t* vp = Vg + base + (size_t)sr * 1024 + h * 64 + sc;
        vr0 = *(const bf16x8*)&vp[0];
        vr1 = *(const bf16x8*)&vp[8];
    }

    bf16_t* PwA = &Ps[(w * 2 + 0) * PW_REGION];
    bf16_t* PwB = &Ps[(w * 2 + 1) * PW_REGION];
    const float SCL = 0.125f * 1.44269504088896f;

    for (int kt = 0; kt <= last; kt++) {
        if (kt > 0) __syncthreads();
        *(bf16x8*)&Ks[sr * 72 + sc]     = kr0;
        *(bf16x8*)&Ks[sr * 72 + sc + 8] = kr1;
#pragma unroll
        for (int e = 0; e < 8; e++) Vt[vtbase + e * 72]       = vr0[e];
#pragma unroll
        for (int e = 0; e < 8; e++) Vt[vtbase + (e + 8) * 72] = vr1[e];
        __syncthreads();

        if (kt < last) {
            const bf16_t* kp = Kg + base + (size_t)((kt + 1) * 64 + sr) * 1024 + h * 64 + sc;
            kr0 = *(const bf16x8*)&kp[0];
            kr1 = *(const bf16x8*)&kp[8];
            const bf16_t* vp = Vg + base + (size_t)((kt + 1) * 64 + sr) * 1024 + h * 64 + sc;
            vr0 = *(const bf16x8*)&vp[0];
            vr1 = *(const bf16x8*)&vp[8];
        }

        const bool doA = (kt <= 2 * qb);

        f32x4 sA[4], sB[4];
#pragma unroll
        for (int j = 0; j < 4; j++) {
            f32x4 z = {0.f, 0.f, 0.f, 0.f};
            sA[j] = z; sB[j] = z;
        }
#pragma unroll
        for (int kk = 0; kk < 2; kk++) {
            bf16x8 kf[4];
#pragma unroll
            for (int j = 0; j < 4; j++)
                kf[j] = *(const bf16x8*)&Ks[(j * 16 + c) * 72 + kk * 32 + g * 8];
            if (doA) {
#pragma unroll
                for (int j = 0; j < 4; j++)
                    sA[j] = MFMA_BF16(kf[j], qfA[kk], sA[j], 0, 0, 0);
            }
#pragma unroll
            for (int j = 0; j < 4; j++)
                sB[j] = MFMA_BF16(kf[j], qfB[kk], sB[j], 0, 0, 0);
        }

        if (doA) {
#pragma unroll
            for (int j = 0; j < 4; j++)
#pragma unroll
                for (int r = 0; r < 4; r++) sA[j][r] *= SCL;
            if (kt == 2 * qb) {
#pragma unroll
                for (int j = 0; j < 4; j++)
#pragma unroll
                    for (int r = 0; r < 4; r++)
                        if (j * 16 + g * 4 + r > w * 16 + c) sA[j][r] = NEG_BIG;
            }
            float mx;
            {
                float a0 = fmaxf(fmaxf(sA[0][0], sA[0][1]), fmaxf(sA[0][2], sA[0][3]));
                float a1 = fmaxf(fmaxf(sA[1][0], sA[1][1]), fmaxf(sA[1][2], sA[1][3]));
                float a2 = fmaxf(fmaxf(sA[2][0], sA[2][1]), fmaxf(sA[2][2], sA[2][3]));
                float a3 = fmaxf(fmaxf(sA[3][0], sA[3][1]), fmaxf(sA[3][2], sA[3][3]));
                mx = fmaxf(fmaxf(a0, a1), fmaxf(a2, a3));
                mx = fmaxf(mx, __shfl_xor(mx, 16));
                mx = fmaxf(mx, __shfl_xor(mx, 32));
            }
            if (!__all(mx <= mA + 8.0f)) {
                float mnew  = fmaxf(mA, mx);
                float alpha = EXP2F(mA - mnew);
                mA = mnew;
#pragma unroll
                for (int jd = 0; jd < 4; jd++)
#pragma unroll
                    for (int r = 0; r < 4; r++) accA[jd][r] *= alpha;
                lA[0] *= alpha;
            }
#pragma unroll
            for (int j = 0; j < 4; j++)
#pragma unroll
                for (int r = 0; r < 4; r++) sA[j][r] = EXP2F(sA[j][r] - mA);
#pragma unroll
            for (int j = 0; j < 4; j++) {
                bf16x4 pk;
#pragma unroll
                for (int r = 0; r < 4; r++) pk[r] = (bf16_t)sA[j][r];
                *(bf16x4*)&PwA[PS_IDX(c, j * 16 + g * 4)] = pk;
            }
        }

        {
#pragma unroll
            for (int j = 0; j < 4; j++)
#pragma unroll
                for (int r = 0; r < 4; r++) sB[j][r] *= SCL;
            if (kt == last) {
#pragma unroll
                for (int j = 0; j < 4; j++)
#pragma unroll
                    for (int r = 0; r < 4; r++)
                        if (j * 16 + g * 4 + r > w * 16 + c) sB[j][r] = NEG_BIG;
            }
            float mx;
            {
                float a0 = fmaxf(fmaxf(sB[0][0], sB[0][1]), fmaxf(sB[0][2], sB[0][3]));
                float a1 = fmaxf(fmaxf(sB[1][0], sB[1][1]), fmaxf(sB[1][2], sB[1][3]));
                float a2 = fmaxf(fmaxf(sB[2][0], sB[2][1]), fmaxf(sB[2][2], sB[2][3]));
                float a3 = fmaxf(fmaxf(sB[3][0], sB[3][1]), fmaxf(sB[3][2], sB[3][3]));
                mx = fmaxf(fmaxf(a0, a1), fmaxf(a2, a3));
                mx = fmaxf(mx, __shfl_xor(mx, 16));
                mx = fmaxf(mx, __shfl_xor(mx, 32));
            }
            if (!__all(mx <= mB + 8.0f)) {
                float mnew  = fmaxf(mB, mx);
                float alpha = EXP2F(mB - mnew);
                mB = mnew;
#pragma unroll
                for (int jd = 0; jd < 4; jd++)
#pragma unroll
                    for (int r = 0; r < 4; r++) accB[jd][r] *= alpha;
                lB[0] *= alpha;
            }
#pragma unroll
            for (int j = 0; j < 4; j++)
#pragma unroll
                for (int r = 0; r < 4; r++) sB[j][r] = EXP2F(sB[j][r] - mB);
#pragma unroll
            for (int j = 0; j < 4; j++) {
                bf16x4 pk;
#pragma unroll
                for (int r = 0; r < 4; r++) pk[r] = (bf16_t)sB[j][r];
                *(bf16x4*)&PwB[PS_IDX(c, j * 16 + g * 4)] = pk;
            }
        }

#pragma unroll
        for (int kkv = 0; kkv < 2; kkv++) {
            bf16x8 vf[4];
#pragma unroll
            for (int jd = 0; jd < 4; jd++)
                vf[jd] = *(const bf16x8*)&Vt[VT_IDX(jd * 16 + c, kkv * 32 + g * 8)];
            if (doA) {
                bf16x8 pfA = *(const bf16x8*)&PwA[PS_IDX(c, kkv * 32 + g * 8)];
#pragma unroll
                for (int jd = 0; jd < 4; jd++)
                    accA[jd] = MFMA_BF16(vf[jd], pfA, accA[jd], 0, 0, 0);
                lA = MFMA_BF16(ones, pfA, lA, 0, 0, 0);
            }
            bf16x8 pfB = *(const bf16x8*)&PwB[PS_IDX(c, kkv * 32 + g * 8)];
#pragma unroll
            for (int jd = 0; jd < 4; jd++)
                accB[jd] = MFMA_BF16(vf[jd], pfB, accB[jd], 0, 0, 0);
            lB = MFMA_BF16(ones, pfB, lB, 0, 0, 0);
        }
    }

    {
        float rl = 1.0f / lA[0];
        bf16_t* op = Q + base + (size_t)(q0 + w * 16 + c) * 1024 + h * 64;
#pragma unroll
        for (int jd = 0; jd < 4; jd++) {
            bf16x4 o4;
#pragma unroll
            for (int r = 0; r < 4; r++) o4[r] = (bf16_t)(accA[jd][r] * rl);
            *(bf16x4*)&op[jd * 16 + g * 4] = o4;
        }
    }
    {
        float rl = 1.0f / lB[0];
        bf16_t* op = Q + base + (size_t)(q0 + 64 + w * 16 + c) * 1024 + h * 64;
#pragma unroll
        for (int jd = 0; jd < 4; jd++) {
            bf16x4 o4;
#pragma unroll
            for (int r = 0; r < 4; r++) o4[r] = (bf16_t)(accB[jd][r] * rl);
            *(bf16x4*)&op[jd * 16 + g * 4] = o4;
        }
    }
}

// ---------------------------------------------------------------------------
extern "C" void kernel_launch(void* const* d_in, const int* in_sizes, int n_in,
                              void* d_out, int out_size, void* d_ws, size_t ws_size,
                              hipStream_t stream) {
    const float* x     = (const float*)d_in[0];
    const float* Wqkv  = (const float*)d_in[1];
    const float* bqkv  = (const float*)d_in[2];
    const float* Aqkv  = (const float*)d_in[3];
    const float* Bqkv  = (const float*)d_in[4];
    const float* Wproj = (const float*)d_in[5];
    const float* bproj = (const float*)d_in[6];
    const float* Aproj = (const float*)d_in[7];
    const float* Bproj = (const float*)d_in[8];
    float* out = (float*)d_out;

    char* ws = (char*)d_ws;
    const bool big = ws_size >= (size_t)(72.5 * 1024 * 1024) + 65536;

    if (big) {
        float*  xa1    = (float*)ws;
        float*  xa2    = (float*)(ws + 262144);
        bf16_t* x16    = (bf16_t*)(ws + 524288);
        bf16_t* Wqkv16 = x16 + (size_t)8192 * 1024;
        bf16_t* Wproj16= Wqkv16 + (size_t)3072 * 1024;
        bf16_t* Qfull  = Wproj16 + (size_t)1024 * 1024;
        bf16_t* Kfull  = Qfull + (size_t)8192 * 1024;
        bf16_t* Vfull  = Kfull + (size_t)8192 * 1024;

        prep_kernel<<<8192, 256, 0, stream>>>(
            x, Wqkv, Wproj, x16, Wqkv16, Wproj16, Aqkv, xa1);

        gemm_256<<<384, 512, 0, stream>>>(
            x16, Wqkv16, bqkv, xa1, Bqkv, Qfull, Kfull, Vfull, nullptr, 1024, 12);

        attn_kernel<<<1024, 256, 0, stream>>>(Qfull, Kfull, Vfull);

        lora_xa_kernel<bf16_t><<<2048, 256, 0, stream>>>(Qfull, Aproj, xa2);

        gemm_async<<<dim3(8, 64), 256, 0, stream>>>(
            Qfull, Wproj16, bproj, xa2, Bproj,
            nullptr, nullptr, nullptr, out, 1024);
    } else {
        float*  xa1   = (float*)ws;
        float*  xa2   = (float*)(ws + 262144);
        bf16_t* Qfull = (bf16_t*)(ws + 524288);
        bf16_t* Kfull = Qfull + (size_t)8192 * 1024;
        bf16_t* Vfull = Kfull + (size_t)8192 * 1024;

        lora_xa_kernel<float><<<2048, 256, 0, stream>>>(x, Aqkv, xa1);
        gemm_bias_lora<float, float><<<dim3(24, 64), 256, 0, stream>>>(
            x, Wqkv, bqkv, xa1, Bqkv, Qfull, Kfull, Vfull, nullptr, 1024);
        attn_kernel<<<1024, 256, 0, stream>>>(Qfull, Kfull, Vfull);
        lora_xa_kernel<bf16_t><<<2048, 256, 0, stream>>>(Qfull, Aproj, xa2);
        gemm_bias_lora<bf16_t, float><<<dim3(8, 64), 256, 0, stream>>>(
            Qfull, Wproj, bproj, xa2, Bproj,
            nullptr, nullptr, nullptr, out, 1024);
    }
}

// Round 8
// 301.140 us; speedup vs baseline: 1.1338x; 1.0491x over previous
//
#include <hip/hip_runtime.h>
#include <hip/hip_bf16.h>

typedef __bf16 bf16_t;
typedef __bf16 bf16x8 __attribute__((ext_vector_type(8)));
typedef __bf16 bf16x4 __attribute__((ext_vector_type(4)));
typedef float  f32x4  __attribute__((ext_vector_type(4)));

#define MFMA_BF16 __builtin_amdgcn_mfma_f32_16x16x32_bf16
#define NEG_BIG  (-3.0e38f)

#if __has_builtin(__builtin_amdgcn_exp2f)
#define EXP2F(x) __builtin_amdgcn_exp2f(x)
#else
#define EXP2F(x) exp2f(x)
#endif

#define SBAR()       __builtin_amdgcn_s_barrier()
#define SCHED0()     __builtin_amdgcn_sched_barrier(0)
#define WAIT_LGKM0() asm volatile("s_waitcnt lgkmcnt(0)" ::: "memory")
#define WAIT_LGKM8() asm volatile("s_waitcnt lgkmcnt(8)" ::: "memory")
#define WAIT_VM0()   asm volatile("s_waitcnt vmcnt(0)" ::: "memory")
#define WAIT_VM4()   asm volatile("s_waitcnt vmcnt(4)" ::: "memory")
#define WAIT_VM6()   asm volatile("s_waitcnt vmcnt(6)" ::: "memory")

// async global->LDS 16B copy (gfx950 dwordx4 variant)
__device__ __forceinline__ void load16_lds(const bf16_t* g, bf16_t* l) {
    __builtin_amdgcn_global_load_lds(
        (const __attribute__((address_space(1))) void*)g,
        (__attribute__((address_space(3))) void*)l, 16, 0, 0);
}

// load 8 contiguous elements as bf16x8, converting if source is fp32
__device__ inline bf16x8 ld8(const bf16_t* p) { return *(const bf16x8*)p; }
__device__ inline bf16x8 ld8(const float* p) {
    f32x4 a = *(const f32x4*)p;
    f32x4 b = *(const f32x4*)(p + 4);
    bf16x8 o;
    o[0] = (bf16_t)a[0]; o[1] = (bf16_t)a[1]; o[2] = (bf16_t)a[2]; o[3] = (bf16_t)a[3];
    o[4] = (bf16_t)b[0]; o[5] = (bf16_t)b[1]; o[6] = (bf16_t)b[2]; o[7] = (bf16_t)b[3];
    return o;
}

// ---------------------------------------------------------------------------
// LoRA first stage body: out[m][r] = sum_k X[m][k] * A[r][k]
// ---------------------------------------------------------------------------
template <typename TX>
__device__ __forceinline__ void lora_xa_body(
    const TX* __restrict__ X, const float* __restrict__ A,
    float* __restrict__ out, int m, int lane)
{
    const TX* xp = X + (size_t)m * 1024;
    float acc[8];
#pragma unroll
    for (int r = 0; r < 8; r++) acc[r] = 0.f;

#pragma unroll 4
    for (int ci = 0; ci < 16; ci++) {
        int k = ci * 64 + lane;
        float xv = (float)xp[k];
#pragma unroll
        for (int r = 0; r < 8; r++) acc[r] += xv * A[r * 1024 + k];
    }
#pragma unroll
    for (int r = 0; r < 8; r++) {
        float v = acc[r];
        v += __shfl_xor(v, 1);  v += __shfl_xor(v, 2);  v += __shfl_xor(v, 4);
        v += __shfl_xor(v, 8);  v += __shfl_xor(v, 16); v += __shfl_xor(v, 32);
        if (lane == 0) out[m * 8 + r] = v;
    }
}

template <typename TX>
__global__ __launch_bounds__(256) void lora_xa_kernel(
    const TX* __restrict__ X, const float* __restrict__ A,
    float* __restrict__ out)
{
    const int lane = threadIdx.x & 63;
    const int w    = threadIdx.x >> 6;
    const int m    = blockIdx.x * 4 + w;
    lora_xa_body<TX>(X, A, out, m, lane);
}

// ---------------------------------------------------------------------------
// Fused prep: fp32->bf16 converts for x / Wqkv / Wproj + first-stage LoRA
// ---------------------------------------------------------------------------
__global__ __launch_bounds__(256) void prep_kernel(
    const float* __restrict__ x, const float* __restrict__ Wqkv,
    const float* __restrict__ Wproj,
    bf16_t* __restrict__ x16, bf16_t* __restrict__ Wqkv16,
    bf16_t* __restrict__ Wproj16,
    const float* __restrict__ Aqkv, float* __restrict__ xa1)
{
    const int bid = blockIdx.x;
    if (bid < 6144) {
        const float* in; bf16_t* out; size_t off;
        if (bid < 4096)      { in = x;     out = x16;     off = (size_t)bid * 2048; }
        else if (bid < 5632) { in = Wqkv;  out = Wqkv16;  off = (size_t)(bid - 4096) * 2048; }
        else                 { in = Wproj; out = Wproj16; off = (size_t)(bid - 5632) * 2048; }
        size_t i = off + (size_t)threadIdx.x * 8;
        *(bf16x8*)&out[i] = ld8(&in[i]);
    } else {
        const int lane = threadIdx.x & 63;
        const int w    = threadIdx.x >> 6;
        const int m    = (bid - 6144) * 4 + w;
        lora_xa_body<float>(x, Aqkv, xa1, m, lane);
    }
}

// ---------------------------------------------------------------------------
// Shared epilogue for 4x4 acc (128-tile fallback kernel)
// ---------------------------------------------------------------------------
__device__ __forceinline__ void gemm_epilogue(
    f32x4 (&acc)[4][4], const float* bias, const float* xA, const float* LB,
    bf16_t* C0, bf16_t* C1, bf16_t* C2, float* Cf,
    int tile_m, int tile_n, int wm, int wn, int c, int g)
{
    const int seg    = tile_n >> 10;
    const int tn_loc = tile_n & 1023;
    bf16_t* Cout = (seg == 0) ? C0 : (seg == 1) ? C1 : C2;

    float biasf[4];
    float lbv[4][8];
#pragma unroll
    for (int j = 0; j < 4; j++) {
        int col = tile_n + wn + j * 16 + c;
        biasf[j] = bias[col];
        f32x4 lb0 = *(const f32x4*)&LB[(size_t)col * 8];
        f32x4 lb1 = *(const f32x4*)&LB[(size_t)col * 8 + 4];
#pragma unroll
        for (int r = 0; r < 4; r++) { lbv[j][r] = lb0[r]; lbv[j][r + 4] = lb1[r]; }
    }
#pragma unroll
    for (int i = 0; i < 4; i++) {
#pragma unroll
        for (int rg = 0; rg < 4; rg++) {
            int row = tile_m + wm + i * 16 + g * 4 + rg;
            f32x4 xa0 = *(const f32x4*)&xA[(size_t)row * 8];
            f32x4 xa1 = *(const f32x4*)&xA[(size_t)row * 8 + 4];
#pragma unroll
            for (int j = 0; j < 4; j++) {
                float lora = xa0[0] * lbv[j][0] + xa0[1] * lbv[j][1] +
                             xa0[2] * lbv[j][2] + xa0[3] * lbv[j][3] +
                             xa1[0] * lbv[j][4] + xa1[1] * lbv[j][5] +
                             xa1[2] * lbv[j][6] + xa1[3] * lbv[j][7];
                float v = acc[i][j][rg] + biasf[j] + 2.0f * lora;
                int lcol = tn_loc + wn + j * 16 + c;
                if (Cf) Cf[(size_t)row * 1024 + lcol] = v;
                else    Cout[(size_t)row * 1024 + lcol] = (bf16_t)v;
            }
        }
    }
}

// ---------------------------------------------------------------------------
// FALLBACK GEMM (small-ws path): VGPR staging, inline fp32->bf16 cvt.
// ---------------------------------------------------------------------------
template <typename TA, typename TW>
__global__ __launch_bounds__(256) void gemm_bias_lora(
    const TA* __restrict__ A, const TW* __restrict__ W,
    const float* __restrict__ bias, const float* __restrict__ xA,
    const float* __restrict__ LB,
    bf16_t* __restrict__ C0, bf16_t* __restrict__ C1, bf16_t* __restrict__ C2,
    float* __restrict__ Cf, int K)
{
    __shared__ __align__(16) bf16_t As[128 * 72];
    __shared__ __align__(16) bf16_t Bs[128 * 72];

    const int t    = threadIdx.x;
    const int lane = t & 63;
    const int w    = t >> 6;
    const int wm   = (w >> 1) * 64;
    const int wn   = (w & 1) * 64;
    const int c    = lane & 15;
    const int g    = lane >> 4;
    const int tile_m = blockIdx.y * 128;
    const int tile_n = blockIdx.x * 128;

    const int srow = t >> 3;
    const int scol = (t & 7) * 8;

    f32x4 acc[4][4];
#pragma unroll
    for (int i = 0; i < 4; i++)
#pragma unroll
        for (int j = 0; j < 4; j++) {
            f32x4 z = {0.f, 0.f, 0.f, 0.f};
            acc[i][j] = z;
        }

    for (int k0 = 0; k0 < K; k0 += 64) {
#pragma unroll
        for (int i = 0; i < 4; i++) {
            int r = srow + i * 32;
            *(bf16x8*)&As[r * 72 + scol] = ld8(&A[(size_t)(tile_m + r) * K + k0 + scol]);
            *(bf16x8*)&Bs[r * 72 + scol] = ld8(&W[(size_t)(tile_n + r) * K + k0 + scol]);
        }
        __syncthreads();

#pragma unroll
        for (int kk = 0; kk < 2; kk++) {
            bf16x8 af[4], bfr[4];
#pragma unroll
            for (int i = 0; i < 4; i++)
                af[i] = *(const bf16x8*)&As[(wm + i * 16 + c) * 72 + kk * 32 + g * 8];
#pragma unroll
            for (int j = 0; j < 4; j++)
                bfr[j] = *(const bf16x8*)&Bs[(wn + j * 16 + c) * 72 + kk * 32 + g * 8];
#pragma unroll
            for (int i = 0; i < 4; i++)
#pragma unroll
                for (int j = 0; j < 4; j++)
                    acc[i][j] = MFMA_BF16(af[i], bfr[j], acc[i][j], 0, 0, 0);
        }
        __syncthreads();
    }
    gemm_epilogue(acc, bias, xA, LB, C0, C1, C2, Cf, tile_m, tile_n, wm, wn, c, g);
}

// ---------------------------------------------------------------------------
// PROJ GEMM with FUSED second-stage LoRA (per-block local xa2, no atomics).
//   m97 structure (global_load_lds, XOR slot swizzle), 128x128 tile, fp32 out.
//   Extra per K-step: 4 MFMA/wave computing xa2_part(rows w*32..+32, r=0..7)
//   from the SAME staged As tile x Ap^T fragment (Aproj converted to LDS
//   bf16 once per block).  After the K-loop, frags are redistributed via
//   LDS (reusing As) and consumed by the epilogue — no global xa2, no
//   lora_xa kernel, no extra launch.  Each column-block redundantly
//   computes its rows' xa2 (8x) — cheaper than a 16MB global pass.
// ---------------------------------------------------------------------------
#define AS_OFF(row, q) ((row) * 64 + (((q) ^ ((row) & 7)) * 8))

__global__ __launch_bounds__(256) void gemm_proj_fused(
    const bf16_t* __restrict__ A, const bf16_t* __restrict__ W,
    const float* __restrict__ bias, const float* __restrict__ Ap,
    const float* __restrict__ LB, float* __restrict__ Cf, int K)
{
    __shared__ __align__(16) bf16_t As[128 * 64];
    __shared__ __align__(16) bf16_t Bs[128 * 64];
    __shared__ __align__(16) bf16_t Ap16[8 * 1032];   // padded stride vs bank0

    const int t    = threadIdx.x;
    const int lane = t & 63;
    const int w    = t >> 6;
    const int wm   = (w >> 1) * 64;
    const int wn   = (w & 1) * 64;
    const int c    = lane & 15;
    const int g    = lane >> 4;
    const int tile_m = blockIdx.y * 128;
    const int tile_n = blockIdx.x * 128;

    // convert Aproj (8x1024 f32) -> LDS bf16 once per block
    {
        int r = t >> 5;              // 0..7
        int k = (t & 31) * 32;       // 0..992
        const float* src = Ap + (size_t)r * 1024 + k;
        bf16_t* dst = &Ap16[r * 1032 + k];
#pragma unroll
        for (int e = 0; e < 32; e += 8)
            *(bf16x8*)&dst[e] = ld8(&src[e]);
    }

    const int trow = t >> 3;                   // 0..31
    const int k8   = (t & 7) ^ (trow & 7);     // swizzled k-chunk for staging
    const bf16_t* Ab = A + (size_t)tile_m * K + k8 * 8;
    const bf16_t* Wb = W + (size_t)tile_n * K + k8 * 8;

    f32x4 acc[4][4];
#pragma unroll
    for (int i = 0; i < 4; i++)
#pragma unroll
        for (int j = 0; j < 4; j++) {
            f32x4 z = {0.f, 0.f, 0.f, 0.f};
            acc[i][j] = z;
        }
    f32x4 accx[2];   // xa2 frags: D[row = w*32 + fi*16 + g*4+rg][r = c (c<8)]
    {
        f32x4 z = {0.f, 0.f, 0.f, 0.f};
        accx[0] = z; accx[1] = z;
    }

    for (int k0 = 0; k0 < K; k0 += 64) {
#pragma unroll
        for (int i = 0; i < 4; i++) {
            int row = i * 32 + trow;
            load16_lds(&Ab[(size_t)row * K + k0], &As[(i * 256 + t) * 8]);
            load16_lds(&Wb[(size_t)row * K + k0], &Bs[(i * 256 + t) * 8]);
        }
        __syncthreads();   // drains vmcnt + lgkm (Ap16 writes on first iter)

#pragma unroll
        for (int kk = 0; kk < 2; kk++) {
            bf16x8 af[4], bfr[4];
#pragma unroll
            for (int i = 0; i < 4; i++)
                af[i] = *(const bf16x8*)&As[AS_OFF(wm + i * 16 + c, kk * 4 + g)];
#pragma unroll
            for (int j = 0; j < 4; j++)
                bfr[j] = *(const bf16x8*)&Bs[AS_OFF(wn + j * 16 + c, kk * 4 + g)];
#pragma unroll
            for (int i = 0; i < 4; i++)
#pragma unroll
                for (int j = 0; j < 4; j++)
                    acc[i][j] = MFMA_BF16(af[i], bfr[j], acc[i][j], 0, 0, 0);
            // fused xa2: rows w*32 + fi*16, B = Ap^T fragment (r on lane c)
            bf16x8 apf = *(const bf16x8*)&Ap16[(c & 7) * 1032 + k0 + kk * 32 + g * 8];
#pragma unroll
            for (int fi = 0; fi < 2; fi++) {
                bf16x8 xf = *(const bf16x8*)&As[AS_OFF(w * 32 + fi * 16 + c, kk * 4 + g)];
                accx[fi] = MFMA_BF16(xf, apf, accx[fi], 0, 0, 0);
            }
        }
        __syncthreads();
    }

    // redistribute xa2 fragments via LDS (reuse As: 128 rows x 8 r x f32)
    float* xa2l = (float*)As;
    if (c < 8) {
#pragma unroll
        for (int fi = 0; fi < 2; fi++)
#pragma unroll
            for (int rg = 0; rg < 4; rg++)
                xa2l[(w * 32 + fi * 16 + g * 4 + rg) * 8 + c] = accx[fi][rg];
    }
    __syncthreads();

    // epilogue: bias + rank-8 LoRA (xa2 from LDS) + fp32 store
    float biasf[4];
    float lbv[4][8];
#pragma unroll
    for (int j = 0; j < 4; j++) {
        int col = tile_n + wn + j * 16 + c;
        biasf[j] = bias[col];
        f32x4 lb0 = *(const f32x4*)&LB[(size_t)col * 8];
        f32x4 lb1 = *(const f32x4*)&LB[(size_t)col * 8 + 4];
#pragma unroll
        for (int r = 0; r < 4; r++) { lbv[j][r] = lb0[r]; lbv[j][r + 4] = lb1[r]; }
    }
#pragma unroll
    for (int i = 0; i < 4; i++) {
#pragma unroll
        for (int rg = 0; rg < 4; rg++) {
            int rloc = wm + i * 16 + g * 4 + rg;
            int row  = tile_m + rloc;
            f32x4 xa0 = *(const f32x4*)&xa2l[rloc * 8];
            f32x4 xa1 = *(const f32x4*)&xa2l[rloc * 8 + 4];
#pragma unroll
            for (int j = 0; j < 4; j++) {
                float lora = xa0[0] * lbv[j][0] + xa0[1] * lbv[j][1] +
                             xa0[2] * lbv[j][2] + xa0[3] * lbv[j][3] +
                             xa1[0] * lbv[j][4] + xa1[1] * lbv[j][5] +
                             xa1[2] * lbv[j][6] + xa1[3] * lbv[j][7];
                float v = acc[i][j][rg] + biasf[j] + 2.0f * lora;
                Cf[(size_t)row * 1024 + tile_n + wn + j * 16 + c] = v;
            }
        }
    }
}

// ---------------------------------------------------------------------------
// 256x256 GEMM — round-4 proven version (unchanged).
// ---------------------------------------------------------------------------
__global__ __launch_bounds__(512, 2) void gemm_256(
    const bf16_t* __restrict__ A, const bf16_t* __restrict__ W,
    const float* __restrict__ bias, const float* __restrict__ xA,
    const float* __restrict__ LB,
    bf16_t* __restrict__ C0, bf16_t* __restrict__ C1, bf16_t* __restrict__ C2,
    float* __restrict__ Cf, int K, int ntn)
{
    __shared__ __align__(16) bf16_t As[4][8192];   // [buf*2+half][128*64]
    __shared__ __align__(16) bf16_t Bs[4][8192];

    const int t    = threadIdx.x;
    const int lane = t & 63;
    const int w    = t >> 6;
    const int c    = lane & 15;
    const int g    = lane >> 4;

    const int nwg = gridDim.x;
    const int cpx = nwg >> 3;
    const int bid = blockIdx.x;
    const int swz = (bid & 7) * cpx + (bid >> 3);
    const int tile_m = (swz / ntn) * 256;
    const int tile_n = (swz % ntn) * 256;

    const int wm  = (w >> 2) * 128;
    const int wn  = (w & 3) * 64;
    const int ha  = w >> 2;
    const int hb  = wn >> 7;
    const int wnl = wn & 127;

    int aoffs[8][2], boffs[4][2];
#pragma unroll
    for (int il = 0; il < 8; il++) {
        int rl = il * 16 + c;
#pragma unroll
        for (int ks = 0; ks < 2; ks++)
            aoffs[il][ks] = rl * 64 + (((ks * 4 + g) ^ (rl & 7)) * 8);
    }
#pragma unroll
    for (int j2 = 0; j2 < 4; j2++) {
        int rl = wnl + j2 * 16 + c;
#pragma unroll
        for (int ks = 0; ks < 2; ks++)
            boffs[j2][ks] = rl * 64 + (((ks * 4 + g) ^ (rl & 7)) * 8);
    }

    const int trow = t >> 3;
    const int qq   = (t & 7) ^ (trow & 7);
    const bf16_t* aO = A + (size_t)(tile_m + trow) * K + qq * 8;
    const bf16_t* wO = W + (size_t)(tile_n + trow) * K + qq * 8;
    const size_t rK64 = (size_t)64 * K;

#define STAGE_A(T, h) do {                                                         \
    load16_lds(aO + (size_t)(h) * 128 * K + (size_t)(T) * 64,                      \
               &As[((T) & 1) * 2 + (h)][t * 8]);                                   \
    load16_lds(aO + (size_t)(h) * 128 * K + rK64 + (size_t)(T) * 64,               \
               &As[((T) & 1) * 2 + (h)][4096 + t * 8]); } while (0)
#define STAGE_B(T, h) do {                                                         \
    load16_lds(wO + (size_t)(h) * 128 * K + (size_t)(T) * 64,                      \
               &Bs[((T) & 1) * 2 + (h)][t * 8]);                                   \
    load16_lds(wO + (size_t)(h) * 128 * K + rK64 + (size_t)(T) * 64,               \
               &Bs[((T) & 1) * 2 + (h)][4096 + t * 8]); } while (0)

    f32x4 acc[8][4];
#pragma unroll
    for (int i = 0; i < 8; i++)
#pragma unroll
        for (int j2 = 0; j2 < 4; j2++) {
            f32x4 z = {0.f, 0.f, 0.f, 0.f};
            acc[i][j2] = z;
        }

    const int NT = K >> 6;

    STAGE_B(0, 0); STAGE_B(0, 1); STAGE_A(0, 0); STAGE_A(0, 1);
    WAIT_VM4();
    STAGE_B(1, 0); STAGE_B(1, 1); STAGE_A(1, 0);
    WAIT_VM6();
    SBAR();

    for (int j = 0; j < NT; j++) {
        const bf16_t* Ab = &As[(j & 1) * 2 + ha][0];
        const bf16_t* Bb = &Bs[(j & 1) * 2 + hb][0];
        bf16x8 bfr[4][2], af0[4], af1[4];

#pragma unroll
        for (int j2 = 0; j2 < 4; j2++) {
            bfr[j2][0] = *(const bf16x8*)&Bb[boffs[j2][0]];
            bfr[j2][1] = *(const bf16x8*)&Bb[boffs[j2][1]];
        }
#pragma unroll
        for (int i = 0; i < 4; i++) af0[i] = *(const bf16x8*)&Ab[aoffs[i][0]];
        if (j + 1 < NT) STAGE_A(j + 1, 1);
        WAIT_LGKM8();
        SBAR();
        WAIT_LGKM0();
        SCHED0();
        __builtin_amdgcn_s_setprio(1);
#pragma unroll
        for (int i = 0; i < 4; i++)
#pragma unroll
            for (int j2 = 0; j2 < 4; j2++)
                acc[i][j2] = MFMA_BF16(af0[i], bfr[j2][0], acc[i][j2], 0, 0, 0);
        __builtin_amdgcn_s_setprio(0);
        SBAR();

#pragma unroll
        for (int i = 0; i < 4; i++) af1[i] = *(const bf16x8*)&Ab[aoffs[i + 4][0]];
        if (j + 2 < NT) STAGE_B(j + 2, 0);
        SBAR();
        WAIT_LGKM0();
        SCHED0();
        __builtin_amdgcn_s_setprio(1);
#pragma unroll
        for (int i = 0; i < 4; i++)
#pragma unroll
            for (int j2 = 0; j2 < 4; j2++)
                acc[4 + i][j2] = MFMA_BF16(af1[i], bfr[j2][0], acc[4 + i][j2], 0, 0, 0);
        __builtin_amdgcn_s_setprio(0);
        SBAR();

#pragma unroll
        for (int i = 0; i < 4; i++) af0[i] = *(const bf16x8*)&Ab[aoffs[i][1]];
#pragma unroll
        for (int i = 0; i < 4; i++) af1[i] = *(const bf16x8*)&Ab[aoffs[i + 4][1]];
        if (j + 2 < NT) STAGE_B(j + 2, 1);
        SBAR();
        WAIT_LGKM0();
        SCHED0();
        __builtin_amdgcn_s_setprio(1);
#pragma unroll
        for (int i = 0; i < 4; i++)
#pragma unroll
            for (int j2 = 0; j2 < 4; j2++)
                acc[i][j2] = MFMA_BF16(af0[i], bfr[j2][1], acc[i][j2], 0, 0, 0);
        __builtin_amdgcn_s_setprio(0);
        SBAR();

        if (j + 2 < NT) STAGE_A(j + 2, 0);
        SBAR();
        __builtin_amdgcn_s_setprio(1);
#pragma unroll
        for (int i = 0; i < 4; i++)
#pragma unroll
            for (int j2 = 0; j2 < 4; j2++)
                acc[4 + i][j2] = MFMA_BF16(af1[i], bfr[j2][1], acc[4 + i][j2], 0, 0, 0);
        __builtin_amdgcn_s_setprio(0);
        if (j < NT - 2) WAIT_VM6(); else WAIT_VM0();
        SBAR();
    }
#undef STAGE_A
#undef STAGE_B

    const int seg    = tile_n >> 10;
    const int tn_loc = tile_n & 1023;
    bf16_t* Cout = (seg == 0) ? C0 : (seg == 1) ? C1 : C2;

    float biasf[4];
    float lbv[4][8];
#pragma unroll
    for (int j2 = 0; j2 < 4; j2++) {
        int col = tile_n + wn + j2 * 16 + c;
        biasf[j2] = bias[col];
        f32x4 lb0 = *(const f32x4*)&LB[(size_t)col * 8];
        f32x4 lb1 = *(const f32x4*)&LB[(size_t)col * 8 + 4];
#pragma unroll
        for (int r = 0; r < 4; r++) { lbv[j2][r] = lb0[r]; lbv[j2][r + 4] = lb1[r]; }
    }
#pragma unroll
    for (int i = 0; i < 8; i++) {
#pragma unroll
        for (int rg = 0; rg < 4; rg++) {
            int row = tile_m + wm + i * 16 + g * 4 + rg;
            f32x4 xa0 = *(const f32x4*)&xA[(size_t)row * 8];
            f32x4 xa1 = *(const f32x4*)&xA[(size_t)row * 8 + 4];
#pragma unroll
            for (int j2 = 0; j2 < 4; j2++) {
                float lora = xa0[0] * lbv[j2][0] + xa0[1] * lbv[j2][1] +
                             xa0[2] * lbv[j2][2] + xa0[3] * lbv[j2][3] +
                             xa1[0] * lbv[j2][4] + xa1[1] * lbv[j2][5] +
                             xa1[2] * lbv[j2][6] + xa1[3] * lbv[j2][7];
                float v = acc[i][j2][rg] + biasf[j2] + 2.0f * lora;
                int lcol = tn_loc + wn + j2 * 16 + c;
                if (Cf) Cf[(size_t)row * 1024 + lcol] = v;
                else    Cout[(size_t)row * 1024 + lcol] = (bf16_t)v;
            }
        }
    }
}

// ---------------------------------------------------------------------------
// Causal flash attention, QBLK=128 two-strip form (round-7, verified).
// ---------------------------------------------------------------------------
#define VT_IDX(d, kv) ((d) * 72 + ((d) >> 4) * 16 + (kv))
#define PS_IDX(q, kv) ((q) * 72 + ((q) >> 2) * 8 + (kv))
#define PW_REGION 1168

__global__ __launch_bounds__(256, 2) void attn_kernel(
    bf16_t* __restrict__ Q, const bf16_t* __restrict__ Kg,
    const bf16_t* __restrict__ Vg)
{
    __shared__ __align__(16) bf16_t Ks[64 * 72];
    __shared__ __align__(16) bf16_t Vt[64 * 72 + 64];
    __shared__ __align__(16) bf16_t Ps[8 * PW_REGION];

    const int t    = threadIdx.x;
    const int lane = t & 63;
    const int w    = t >> 6;
    const int c    = lane & 15;
    const int g    = lane >> 4;

    const int id = blockIdx.x;
    const int qb = 15 - (id >> 6);
    const int h  = id & 15;
    const int b  = (id >> 4) & 3;
    const int q0 = qb * 128;
    const size_t base = (size_t)b * 2048 * 1024;
    const int last = 2 * qb + 1;

    bf16x8 qfA[2], qfB[2];
    {
        const bf16_t* qpA = Q + base + (size_t)(q0 + w * 16 + c) * 1024 + h * 64;
        qfA[0] = *(const bf16x8*)&qpA[g * 8];
        qfA[1] = *(const bf16x8*)&qpA[32 + g * 8];
        const bf16_t* qpB = qpA + (size_t)64 * 1024;
        qfB[0] = *(const bf16x8*)&qpB[g * 8];
        qfB[1] = *(const bf16x8*)&qpB[32 + g * 8];
    }

    bf16x8 ones;
#pragma unroll
    for (int e = 0; e < 8; e++) ones[e] = (bf16_t)1.0f;

    f32x4 accA[4], accB[4];
#pragma unroll
    for (int jd = 0; jd < 4; jd++) {
        f32x4 z = {0.f, 0.f, 0.f, 0.f};
        accA[jd] = z; accB[jd] = z;
    }
    f32x4 lA = {0.f, 0.f, 0.f, 0.f};
    f32x4 lB = {0.f, 0.f, 0.f, 0.f};
    float mA = NEG_BIG, mB = NEG_BIG;

    const int sr = t >> 2;
    const int sc = (t & 3) * 16;
    const int vtbase = VT_IDX(sc, sr);

    bf16x8 kr0, kr1, vr0, vr1;
    {
        const bf16_t* kp = Kg + base + (size_t)sr * 1024 + h * 64 + sc;
        kr0 = *(const bf16x8*)&kp[0];
        kr1 = *(const bf16x8*)&kp[8];
        const bf16_t* vp = Vg + base + (size_t)sr * 1024 + h * 64 + sc;
        vr0 = *(const bf16x8*)&vp[0];
        vr1 = *(const bf16x8*)&vp[8];
    }

    bf16_t* PwA = &Ps[(w * 2 + 0) * PW_REGION];
    bf16_t* PwB = &Ps[(w * 2 + 1) * PW_REGION];
    const float SCL = 0.125f * 1.44269504088896f;

    for (int kt = 0; kt <= last; kt++) {
        if (kt > 0) __syncthreads();
        *(bf16x8*)&Ks[sr * 72 + sc]     = kr0;
        *(bf16x8*)&Ks[sr * 72 + sc + 8] = kr1;
#pragma unroll
        for (int e = 0; e < 8; e++) Vt[vtbase + e * 72]       = vr0[e];
#pragma unroll
        for (int e = 0; e < 8; e++) Vt[vtbase + (e + 8) * 72] = vr1[e];
        __syncthreads();

        if (kt < last) {
            const bf16_t* kp = Kg + base + (size_t)((kt + 1) * 64 + sr) * 1024 + h * 64 + sc;
            kr0 = *(const bf16x8*)&kp[0];
            kr1 = *(const bf16x8*)&kp[8];
            const bf16_t* vp = Vg + base + (size_t)((kt + 1) * 64 + sr) * 1024 + h * 64 + sc;
            vr0 = *(const bf16x8*)&vp[0];
            vr1 = *(const bf16x8*)&vp[8];
        }

        const bool doA = (kt <= 2 * qb);

        f32x4 sA[4], sB[4];
#pragma unroll
        for (int j = 0; j < 4; j++) {
            f32x4 z = {0.f, 0.f, 0.f, 0.f};
            sA[j] = z; sB[j] = z;
        }
#pragma unroll
        for (int kk = 0; kk < 2; kk++) {
            bf16x8 kf[4];
#pragma unroll
            for (int j = 0; j < 4; j++)
                kf[j] = *(const bf16x8*)&Ks[(j * 16 + c) * 72 + kk * 32 + g * 8];
            if (doA) {
#pragma unroll
                for (int j = 0; j < 4; j++)
                    sA[j] = MFMA_BF16(kf[j], qfA[kk], sA[j], 0, 0, 0);
            }
#pragma unroll
            for (int j = 0; j < 4; j++)
                sB[j] = MFMA_BF16(kf[j], qfB[kk], sB[j], 0, 0, 0);
        }

        if (doA) {
#pragma unroll
            for (int j = 0; j < 4; j++)
#pragma unroll
                for (int r = 0; r < 4; r++) sA[j][r] *= SCL;
            if (kt == 2 * qb) {
#pragma unroll
                for (int j = 0; j < 4; j++)
#pragma unroll
                    for (int r = 0; r < 4; r++)
                        if (j * 16 + g * 4 + r > w * 16 + c) sA[j][r] = NEG_BIG;
            }
            float mx;
            {
                float a0 = fmaxf(fmaxf(sA[0][0], sA[0][1]), fmaxf(sA[0][2], sA[0][3]));
                float a1 = fmaxf(fmaxf(sA[1][0], sA[1][1]), fmaxf(sA[1][2], sA[1][3]));
                float a2 = fmaxf(fmaxf(sA[2][0], sA[2][1]), fmaxf(sA[2][2], sA[2][3]));
                float a3 = fmaxf(fmaxf(sA[3][0], sA[3][1]), fmaxf(sA[3][2], sA[3][3]));
                mx = fmaxf(fmaxf(a0, a1), fmaxf(a2, a3));
                mx = fmaxf(mx, __shfl_xor(mx, 16));
                mx = fmaxf(mx, __shfl_xor(mx, 32));
            }
            if (!__all(mx <= mA + 8.0f)) {
                float mnew  = fmaxf(mA, mx);
                float alpha = EXP2F(mA - mnew);
                mA = mnew;
#pragma unroll
                for (int jd = 0; jd < 4; jd++)
#pragma unroll
                    for (int r = 0; r < 4; r++) accA[jd][r] *= alpha;
                lA[0] *= alpha;
            }
#pragma unroll
            for (int j = 0; j < 4; j++)
#pragma unroll
                for (int r = 0; r < 4; r++) sA[j][r] = EXP2F(sA[j][r] - mA);
#pragma unroll
            for (int j = 0; j < 4; j++) {
                bf16x4 pk;
#pragma unroll
                for (int r = 0; r < 4; r++) pk[r] = (bf16_t)sA[j][r];
                *(bf16x4*)&PwA[PS_IDX(c, j * 16 + g * 4)] = pk;
            }
        }

        {
#pragma unroll
            for (int j = 0; j < 4; j++)
#pragma unroll
                for (int r = 0; r < 4; r++) sB[j][r] *= SCL;
            if (kt == last) {
#pragma unroll
                for (int j = 0; j < 4; j++)
#pragma unroll
                    for (int r = 0; r < 4; r++)
                        if (j * 16 + g * 4 + r > w * 16 + c) sB[j][r] = NEG_BIG;
            }
            float mx;
            {
                float a0 = fmaxf(fmaxf(sB[0][0], sB[0][1]), fmaxf(sB[0][2], sB[0][3]));
                float a1 = fmaxf(fmaxf(sB[1][0], sB[1][1]), fmaxf(sB[1][2], sB[1][3]));
                float a2 = fmaxf(fmaxf(sB[2][0], sB[2][1]), fmaxf(sB[2][2], sB[2][3]));
                float a3 = fmaxf(fmaxf(sB[3][0], sB[3][1]), fmaxf(sB[3][2], sB[3][3]));
                mx = fmaxf(fmaxf(a0, a1), fmaxf(a2, a3));
                mx = fmaxf(mx, __shfl_xor(mx, 16));
                mx = fmaxf(mx, __shfl_xor(mx, 32));
            }
            if (!__all(mx <= mB + 8.0f)) {
                float mnew  = fmaxf(mB, mx);
                float alpha = EXP2F(mB - mnew);
                mB = mnew;
#pragma unroll
                for (int jd = 0; jd < 4; jd++)
#pragma unroll
                    for (int r = 0; r < 4; r++) accB[jd][r] *= alpha;
                lB[0] *= alpha;
            }
#pragma unroll
            for (int j = 0; j < 4; j++)
#pragma unroll
                for (int r = 0; r < 4; r++) sB[j][r] = EXP2F(sB[j][r] - mB);
#pragma unroll
            for (int j = 0; j < 4; j++) {
                bf16x4 pk;
#pragma unroll
                for (int r = 0; r < 4; r++) pk[r] = (bf16_t)sB[j][r];
                *(bf16x4*)&PwB[PS_IDX(c, j * 16 + g * 4)] = pk;
            }
        }

#pragma unroll
        for (int kkv = 0; kkv < 2; kkv++) {
            bf16x8 vf[4];
#pragma unroll
            for (int jd = 0; jd < 4; jd++)
                vf[jd] = *(const bf16x8*)&Vt[VT_IDX(jd * 16 + c, kkv * 32 + g * 8)];
            if (doA) {
                bf16x8 pfA = *(const bf16x8*)&PwA[PS_IDX(c, kkv * 32 + g * 8)];
#pragma unroll
                for (int jd = 0; jd < 4; jd++)
                    accA[jd] = MFMA_BF16(vf[jd], pfA, accA[jd], 0, 0, 0);
                lA = MFMA_BF16(ones, pfA, lA, 0, 0, 0);
            }
            bf16x8 pfB = *(const bf16x8*)&PwB[PS_IDX(c, kkv * 32 + g * 8)];
#pragma unroll
            for (int jd = 0; jd < 4; jd++)
                accB[jd] = MFMA_BF16(vf[jd], pfB, accB[jd], 0, 0, 0);
            lB = MFMA_BF16(ones, pfB, lB, 0, 0, 0);
        }
    }

    {
        float rl = 1.0f / lA[0];
        bf16_t* op = Q + base + (size_t)(q0 + w * 16 + c) * 1024 + h * 64;
#pragma unroll
        for (int jd = 0; jd < 4; jd++) {
            bf16x4 o4;
#pragma unroll
            for (int r = 0; r < 4; r++) o4[r] = (bf16_t)(accA[jd][r] * rl);
            *(bf16x4*)&op[jd * 16 + g * 4] = o4;
        }
    }
    {
        float rl = 1.0f / lB[0];
        bf16_t* op = Q + base + (size_t)(q0 + 64 + w * 16 + c) * 1024 + h * 64;
#pragma unroll
        for (int jd = 0; jd < 4; jd++) {
            bf16x4 o4;
#pragma unroll
            for (int r = 0; r < 4; r++) o4[r] = (bf16_t)(accB[jd][r] * rl);
            *(bf16x4*)&op[jd * 16 + g * 4] = o4;
        }
    }
}

// ---------------------------------------------------------------------------
extern "C" void kernel_launch(void* const* d_in, const int* in_sizes, int n_in,
                              void* d_out, int out_size, void* d_ws, size_t ws_size,
                              hipStream_t stream) {
    const float* x     = (const float*)d_in[0];
    const float* Wqkv  = (const float*)d_in[1];
    const float* bqkv  = (const float*)d_in[2];
    const float* Aqkv  = (const float*)d_in[3];
    const float* Bqkv  = (const float*)d_in[4];
    const float* Wproj = (const float*)d_in[5];
    const float* bproj = (const float*)d_in[6];
    const float* Aproj = (const float*)d_in[7];
    const float* Bproj = (const float*)d_in[8];
    float* out = (float*)d_out;

    char* ws = (char*)d_ws;
    const bool big = ws_size >= (size_t)(72.5 * 1024 * 1024) + 65536;

    if (big) {
        float*  xa1    = (float*)ws;
        bf16_t* x16    = (bf16_t*)(ws + 524288);
        bf16_t* Wqkv16 = x16 + (size_t)8192 * 1024;
        bf16_t* Wproj16= Wqkv16 + (size_t)3072 * 1024;
        bf16_t* Qfull  = Wproj16 + (size_t)1024 * 1024;
        bf16_t* Kfull  = Qfull + (size_t)8192 * 1024;
        bf16_t* Vfull  = Kfull + (size_t)8192 * 1024;

        prep_kernel<<<8192, 256, 0, stream>>>(
            x, Wqkv, Wproj, x16, Wqkv16, Wproj16, Aqkv, xa1);

        gemm_256<<<384, 512, 0, stream>>>(
            x16, Wqkv16, bqkv, xa1, Bqkv, Qfull, Kfull, Vfull, nullptr, 1024, 12);

        attn_kernel<<<1024, 256, 0, stream>>>(Qfull, Kfull, Vfull);

        // proj GEMM with fused second-stage LoRA (no lora_xa launch)
        gemm_proj_fused<<<dim3(8, 64), 256, 0, stream>>>(
            Qfull, Wproj16, bproj, Aproj, Bproj, out, 1024);
    } else {
        float*  xa1   = (float*)ws;
        float*  xa2   = (float*)(ws + 262144);
        bf16_t* Qfull = (bf16_t*)(ws + 524288);
        bf16_t* Kfull = Qfull + (size_t)8192 * 1024;
        bf16_t* Vfull = Kfull + (size_t)8192 * 1024;

        lora_xa_kernel<float><<<2048, 256, 0, stream>>>(x, Aqkv, xa1);
        gemm_bias_lora<float, float><<<dim3(24, 64), 256, 0, stream>>>(
            x, Wqkv, bqkv, xa1, Bqkv, Qfull, Kfull, Vfull, nullptr, 1024);
        attn_kernel<<<1024, 256, 0, stream>>>(Qfull, Kfull, Vfull);
        lora_xa_kernel<bf16_t><<<2048, 256, 0, stream>>>(Qfull, Aproj, xa2);
        gemm_bias_lora<bf16_t, float><<<dim3(8, 64), 256, 0, stream>>>(
            Qfull, Wproj, bproj, xa2, Bproj,
            nullptr, nullptr, nullptr, out, 1024);
    }
}

// Round 9
// 289.103 us; speedup vs baseline: 1.1810x; 1.0416x over previous
//
#include <hip/hip_runtime.h>
#include <hip/hip_bf16.h>

typedef __bf16 bf16_t;
typedef __bf16 bf16x8 __attribute__((ext_vector_type(8)));
typedef __bf16 bf16x4 __attribute__((ext_vector_type(4)));
typedef float  f32x4  __attribute__((ext_vector_type(4)));

#define MFMA_BF16 __builtin_amdgcn_mfma_f32_16x16x32_bf16
#define NEG_BIG  (-3.0e38f)

#if __has_builtin(__builtin_amdgcn_exp2f)
#define EXP2F(x) __builtin_amdgcn_exp2f(x)
#else
#define EXP2F(x) exp2f(x)
#endif

#define SBAR()       __builtin_amdgcn_s_barrier()
#define SCHED0()     __builtin_amdgcn_sched_barrier(0)
#define WAIT_LGKM0() asm volatile("s_waitcnt lgkmcnt(0)" ::: "memory")
#define WAIT_LGKM8() asm volatile("s_waitcnt lgkmcnt(8)" ::: "memory")
#define WAIT_VM0()   asm volatile("s_waitcnt vmcnt(0)" ::: "memory")
#define WAIT_VM4()   asm volatile("s_waitcnt vmcnt(4)" ::: "memory")
#define WAIT_VM6()   asm volatile("s_waitcnt vmcnt(6)" ::: "memory")

// async global->LDS 16B copy (gfx950 dwordx4 variant)
__device__ __forceinline__ void load16_lds(const bf16_t* g, bf16_t* l) {
    __builtin_amdgcn_global_load_lds(
        (const __attribute__((address_space(1))) void*)g,
        (__attribute__((address_space(3))) void*)l, 16, 0, 0);
}

// load 8 contiguous elements as bf16x8, converting if source is fp32
__device__ inline bf16x8 ld8(const bf16_t* p) { return *(const bf16x8*)p; }
__device__ inline bf16x8 ld8(const float* p) {
    f32x4 a = *(const f32x4*)p;
    f32x4 b = *(const f32x4*)(p + 4);
    bf16x8 o;
    o[0] = (bf16_t)a[0]; o[1] = (bf16_t)a[1]; o[2] = (bf16_t)a[2]; o[3] = (bf16_t)a[3];
    o[4] = (bf16_t)b[0]; o[5] = (bf16_t)b[1]; o[6] = (bf16_t)b[2]; o[7] = (bf16_t)b[3];
    return o;
}

// ---------------------------------------------------------------------------
// LoRA first stage body: out[m][r] = sum_k X[m][k] * A[r][k]
// ---------------------------------------------------------------------------
template <typename TX>
__device__ __forceinline__ void lora_xa_body(
    const TX* __restrict__ X, const float* __restrict__ A,
    float* __restrict__ out, int m, int lane)
{
    const TX* xp = X + (size_t)m * 1024;
    float acc[8];
#pragma unroll
    for (int r = 0; r < 8; r++) acc[r] = 0.f;

#pragma unroll 4
    for (int ci = 0; ci < 16; ci++) {
        int k = ci * 64 + lane;
        float xv = (float)xp[k];
#pragma unroll
        for (int r = 0; r < 8; r++) acc[r] += xv * A[r * 1024 + k];
    }
#pragma unroll
    for (int r = 0; r < 8; r++) {
        float v = acc[r];
        v += __shfl_xor(v, 1);  v += __shfl_xor(v, 2);  v += __shfl_xor(v, 4);
        v += __shfl_xor(v, 8);  v += __shfl_xor(v, 16); v += __shfl_xor(v, 32);
        if (lane == 0) out[m * 8 + r] = v;
    }
}

template <typename TX>
__global__ __launch_bounds__(256) void lora_xa_kernel(
    const TX* __restrict__ X, const float* __restrict__ A,
    float* __restrict__ out)
{
    const int lane = threadIdx.x & 63;
    const int w    = threadIdx.x >> 6;
    const int m    = blockIdx.x * 4 + w;
    lora_xa_body<TX>(X, A, out, m, lane);
}

// ---------------------------------------------------------------------------
// Prep: fp32->bf16 converts for x / Wqkv / Wproj (6144 blocks, big path).
// (lora_xa blocks retained for compatibility if launched with >6144.)
// ---------------------------------------------------------------------------
__global__ __launch_bounds__(256) void prep_kernel(
    const float* __restrict__ x, const float* __restrict__ Wqkv,
    const float* __restrict__ Wproj,
    bf16_t* __restrict__ x16, bf16_t* __restrict__ Wqkv16,
    bf16_t* __restrict__ Wproj16,
    const float* __restrict__ Aqkv, float* __restrict__ xa1)
{
    const int bid = blockIdx.x;
    if (bid < 6144) {
        const float* in; bf16_t* out; size_t off;
        if (bid < 4096)      { in = x;     out = x16;     off = (size_t)bid * 2048; }
        else if (bid < 5632) { in = Wqkv;  out = Wqkv16;  off = (size_t)(bid - 4096) * 2048; }
        else                 { in = Wproj; out = Wproj16; off = (size_t)(bid - 5632) * 2048; }
        size_t i = off + (size_t)threadIdx.x * 8;
        *(bf16x8*)&out[i] = ld8(&in[i]);
    } else {
        const int lane = threadIdx.x & 63;
        const int w    = threadIdx.x >> 6;
        const int m    = (bid - 6144) * 4 + w;
        lora_xa_body<float>(x, Aqkv, xa1, m, lane);
    }
}

// ---------------------------------------------------------------------------
// Shared epilogue for 4x4 acc (128-tile fallback kernel)
// ---------------------------------------------------------------------------
__device__ __forceinline__ void gemm_epilogue(
    f32x4 (&acc)[4][4], const float* bias, const float* xA, const float* LB,
    bf16_t* C0, bf16_t* C1, bf16_t* C2, float* Cf,
    int tile_m, int tile_n, int wm, int wn, int c, int g)
{
    const int seg    = tile_n >> 10;
    const int tn_loc = tile_n & 1023;
    bf16_t* Cout = (seg == 0) ? C0 : (seg == 1) ? C1 : C2;

    float biasf[4];
    float lbv[4][8];
#pragma unroll
    for (int j = 0; j < 4; j++) {
        int col = tile_n + wn + j * 16 + c;
        biasf[j] = bias[col];
        f32x4 lb0 = *(const f32x4*)&LB[(size_t)col * 8];
        f32x4 lb1 = *(const f32x4*)&LB[(size_t)col * 8 + 4];
#pragma unroll
        for (int r = 0; r < 4; r++) { lbv[j][r] = lb0[r]; lbv[j][r + 4] = lb1[r]; }
    }
#pragma unroll
    for (int i = 0; i < 4; i++) {
#pragma unroll
        for (int rg = 0; rg < 4; rg++) {
            int row = tile_m + wm + i * 16 + g * 4 + rg;
            f32x4 xa0 = *(const f32x4*)&xA[(size_t)row * 8];
            f32x4 xa1 = *(const f32x4*)&xA[(size_t)row * 8 + 4];
#pragma unroll
            for (int j = 0; j < 4; j++) {
                float lora = xa0[0] * lbv[j][0] + xa0[1] * lbv[j][1] +
                             xa0[2] * lbv[j][2] + xa0[3] * lbv[j][3] +
                             xa1[0] * lbv[j][4] + xa1[1] * lbv[j][5] +
                             xa1[2] * lbv[j][6] + xa1[3] * lbv[j][7];
                float v = acc[i][j][rg] + biasf[j] + 2.0f * lora;
                int lcol = tn_loc + wn + j * 16 + c;
                if (Cf) Cf[(size_t)row * 1024 + lcol] = v;
                else    Cout[(size_t)row * 1024 + lcol] = (bf16_t)v;
            }
        }
    }
}

// ---------------------------------------------------------------------------
// FALLBACK GEMM (small-ws path): VGPR staging, inline fp32->bf16 cvt.
// ---------------------------------------------------------------------------
template <typename TA, typename TW>
__global__ __launch_bounds__(256) void gemm_bias_lora(
    const TA* __restrict__ A, const TW* __restrict__ W,
    const float* __restrict__ bias, const float* __restrict__ xA,
    const float* __restrict__ LB,
    bf16_t* __restrict__ C0, bf16_t* __restrict__ C1, bf16_t* __restrict__ C2,
    float* __restrict__ Cf, int K)
{
    __shared__ __align__(16) bf16_t As[128 * 72];
    __shared__ __align__(16) bf16_t Bs[128 * 72];

    const int t    = threadIdx.x;
    const int lane = t & 63;
    const int w    = t >> 6;
    const int wm   = (w >> 1) * 64;
    const int wn   = (w & 1) * 64;
    const int c    = lane & 15;
    const int g    = lane >> 4;
    const int tile_m = blockIdx.y * 128;
    const int tile_n = blockIdx.x * 128;

    const int srow = t >> 3;
    const int scol = (t & 7) * 8;

    f32x4 acc[4][4];
#pragma unroll
    for (int i = 0; i < 4; i++)
#pragma unroll
        for (int j = 0; j < 4; j++) {
            f32x4 z = {0.f, 0.f, 0.f, 0.f};
            acc[i][j] = z;
        }

    for (int k0 = 0; k0 < K; k0 += 64) {
#pragma unroll
        for (int i = 0; i < 4; i++) {
            int r = srow + i * 32;
            *(bf16x8*)&As[r * 72 + scol] = ld8(&A[(size_t)(tile_m + r) * K + k0 + scol]);
            *(bf16x8*)&Bs[r * 72 + scol] = ld8(&W[(size_t)(tile_n + r) * K + k0 + scol]);
        }
        __syncthreads();

#pragma unroll
        for (int kk = 0; kk < 2; kk++) {
            bf16x8 af[4], bfr[4];
#pragma unroll
            for (int i = 0; i < 4; i++)
                af[i] = *(const bf16x8*)&As[(wm + i * 16 + c) * 72 + kk * 32 + g * 8];
#pragma unroll
            for (int j = 0; j < 4; j++)
                bfr[j] = *(const bf16x8*)&Bs[(wn + j * 16 + c) * 72 + kk * 32 + g * 8];
#pragma unroll
            for (int i = 0; i < 4; i++)
#pragma unroll
                for (int j = 0; j < 4; j++)
                    acc[i][j] = MFMA_BF16(af[i], bfr[j], acc[i][j], 0, 0, 0);
        }
        __syncthreads();
    }
    gemm_epilogue(acc, bias, xA, LB, C0, C1, C2, Cf, tile_m, tile_n, wm, wn, c, g);
}

// ---------------------------------------------------------------------------
// PROJ GEMM with FUSED second-stage LoRA (round-8, verified).
// ---------------------------------------------------------------------------
#define AS_OFF(row, q) ((row) * 64 + (((q) ^ ((row) & 7)) * 8))

__global__ __launch_bounds__(256) void gemm_proj_fused(
    const bf16_t* __restrict__ A, const bf16_t* __restrict__ W,
    const float* __restrict__ bias, const float* __restrict__ Ap,
    const float* __restrict__ LB, float* __restrict__ Cf, int K)
{
    __shared__ __align__(16) bf16_t As[128 * 64];
    __shared__ __align__(16) bf16_t Bs[128 * 64];
    __shared__ __align__(16) bf16_t Ap16[8 * 1032];   // padded stride vs bank0

    const int t    = threadIdx.x;
    const int lane = t & 63;
    const int w    = t >> 6;
    const int wm   = (w >> 1) * 64;
    const int wn   = (w & 1) * 64;
    const int c    = lane & 15;
    const int g    = lane >> 4;
    const int tile_m = blockIdx.y * 128;
    const int tile_n = blockIdx.x * 128;

    // convert Aproj (8x1024 f32) -> LDS bf16 once per block
    {
        int r = t >> 5;              // 0..7
        int k = (t & 31) * 32;       // 0..992
        const float* src = Ap + (size_t)r * 1024 + k;
        bf16_t* dst = &Ap16[r * 1032 + k];
#pragma unroll
        for (int e = 0; e < 32; e += 8)
            *(bf16x8*)&dst[e] = ld8(&src[e]);
    }

    const int trow = t >> 3;                   // 0..31
    const int k8   = (t & 7) ^ (trow & 7);     // swizzled k-chunk for staging
    const bf16_t* Ab = A + (size_t)tile_m * K + k8 * 8;
    const bf16_t* Wb = W + (size_t)tile_n * K + k8 * 8;

    f32x4 acc[4][4];
#pragma unroll
    for (int i = 0; i < 4; i++)
#pragma unroll
        for (int j = 0; j < 4; j++) {
            f32x4 z = {0.f, 0.f, 0.f, 0.f};
            acc[i][j] = z;
        }
    f32x4 accx[2];   // xa2 frags: D[row = w*32 + fi*16 + g*4+rg][r = c (c<8)]
    {
        f32x4 z = {0.f, 0.f, 0.f, 0.f};
        accx[0] = z; accx[1] = z;
    }

    for (int k0 = 0; k0 < K; k0 += 64) {
#pragma unroll
        for (int i = 0; i < 4; i++) {
            int row = i * 32 + trow;
            load16_lds(&Ab[(size_t)row * K + k0], &As[(i * 256 + t) * 8]);
            load16_lds(&Wb[(size_t)row * K + k0], &Bs[(i * 256 + t) * 8]);
        }
        __syncthreads();   // drains vmcnt + lgkm (Ap16 writes on first iter)

#pragma unroll
        for (int kk = 0; kk < 2; kk++) {
            bf16x8 af[4], bfr[4];
#pragma unroll
            for (int i = 0; i < 4; i++)
                af[i] = *(const bf16x8*)&As[AS_OFF(wm + i * 16 + c, kk * 4 + g)];
#pragma unroll
            for (int j = 0; j < 4; j++)
                bfr[j] = *(const bf16x8*)&Bs[AS_OFF(wn + j * 16 + c, kk * 4 + g)];
#pragma unroll
            for (int i = 0; i < 4; i++)
#pragma unroll
                for (int j = 0; j < 4; j++)
                    acc[i][j] = MFMA_BF16(af[i], bfr[j], acc[i][j], 0, 0, 0);
            // fused xa2: rows w*32 + fi*16, B = Ap^T fragment (r on lane c)
            bf16x8 apf = *(const bf16x8*)&Ap16[(c & 7) * 1032 + k0 + kk * 32 + g * 8];
#pragma unroll
            for (int fi = 0; fi < 2; fi++) {
                bf16x8 xf = *(const bf16x8*)&As[AS_OFF(w * 32 + fi * 16 + c, kk * 4 + g)];
                accx[fi] = MFMA_BF16(xf, apf, accx[fi], 0, 0, 0);
            }
        }
        __syncthreads();
    }

    // redistribute xa2 fragments via LDS (reuse As: 128 rows x 8 r x f32)
    float* xa2l = (float*)As;
    if (c < 8) {
#pragma unroll
        for (int fi = 0; fi < 2; fi++)
#pragma unroll
            for (int rg = 0; rg < 4; rg++)
                xa2l[(w * 32 + fi * 16 + g * 4 + rg) * 8 + c] = accx[fi][rg];
    }
    __syncthreads();

    // epilogue: bias + rank-8 LoRA (xa2 from LDS) + fp32 store
    float biasf[4];
    float lbv[4][8];
#pragma unroll
    for (int j = 0; j < 4; j++) {
        int col = tile_n + wn + j * 16 + c;
        biasf[j] = bias[col];
        f32x4 lb0 = *(const f32x4*)&LB[(size_t)col * 8];
        f32x4 lb1 = *(const f32x4*)&LB[(size_t)col * 8 + 4];
#pragma unroll
        for (int r = 0; r < 4; r++) { lbv[j][r] = lb0[r]; lbv[j][r + 4] = lb1[r]; }
    }
#pragma unroll
    for (int i = 0; i < 4; i++) {
#pragma unroll
        for (int rg = 0; rg < 4; rg++) {
            int rloc = wm + i * 16 + g * 4 + rg;
            int row  = tile_m + rloc;
            f32x4 xa0 = *(const f32x4*)&xa2l[rloc * 8];
            f32x4 xa1 = *(const f32x4*)&xa2l[rloc * 8 + 4];
#pragma unroll
            for (int j = 0; j < 4; j++) {
                float lora = xa0[0] * lbv[j][0] + xa0[1] * lbv[j][1] +
                             xa0[2] * lbv[j][2] + xa0[3] * lbv[j][3] +
                             xa1[0] * lbv[j][4] + xa1[1] * lbv[j][5] +
                             xa1[2] * lbv[j][6] + xa1[3] * lbv[j][7];
                float v = acc[i][j][rg] + biasf[j] + 2.0f * lora;
                Cf[(size_t)row * 1024 + tile_n + wn + j * 16 + c] = v;
            }
        }
    }
}

// ---------------------------------------------------------------------------
// 256x256 QKV GEMM with FUSED first-stage LoRA (xa1 computed from staged
// A-tiles, same no-atomics pattern as gemm_proj_fused).  Per K-tile per
// wave: +2 MFMA (rows ha*128+(w&3)*32 .. +32, r=0..7 on lane c).  Aqkv is
// converted to LDS bf16 once per block; xa1 frags are redistributed via
// 8KB of reused As after the K-loop and consumed by the epilogue (no
// global xa1, no prep-lora blocks).
// ---------------------------------------------------------------------------
__global__ __launch_bounds__(512, 2) void gemm_256(
    const bf16_t* __restrict__ A, const bf16_t* __restrict__ W,
    const float* __restrict__ bias, const float* __restrict__ Aq,
    const float* __restrict__ LB,
    bf16_t* __restrict__ C0, bf16_t* __restrict__ C1, bf16_t* __restrict__ C2,
    float* __restrict__ Cf, int K, int ntn)
{
    __shared__ __align__(16) bf16_t As[4][8192];   // [buf*2+half][128*64]
    __shared__ __align__(16) bf16_t Bs[4][8192];
    __shared__ __align__(16) bf16_t Aq16[8 * 1032];

    const int t    = threadIdx.x;
    const int lane = t & 63;
    const int w    = t >> 6;
    const int c    = lane & 15;
    const int g    = lane >> 4;

    const int nwg = gridDim.x;
    const int cpx = nwg >> 3;
    const int bid = blockIdx.x;
    const int swz = (bid & 7) * cpx + (bid >> 3);
    const int tile_m = (swz / ntn) * 256;
    const int tile_n = (swz % ntn) * 256;

    const int wm  = (w >> 2) * 128;
    const int wn  = (w & 3) * 64;
    const int ha  = w >> 2;
    const int hb  = wn >> 7;
    const int wnl = wn & 127;

    // convert Aqkv (8x1024 f32) -> LDS bf16 once per block (512 thr x 16)
    {
        int r = t >> 6;              // 0..7
        int k = (t & 63) * 16;       // 0..1008
        const float* src = Aq + (size_t)r * 1024 + k;
        bf16_t* dst = &Aq16[r * 1032 + k];
        *(bf16x8*)&dst[0] = ld8(&src[0]);
        *(bf16x8*)&dst[8] = ld8(&src[8]);
    }

    int aoffs[8][2], boffs[4][2];
#pragma unroll
    for (int il = 0; il < 8; il++) {
        int rl = il * 16 + c;
#pragma unroll
        for (int ks = 0; ks < 2; ks++)
            aoffs[il][ks] = rl * 64 + (((ks * 4 + g) ^ (rl & 7)) * 8);
    }
#pragma unroll
    for (int j2 = 0; j2 < 4; j2++) {
        int rl = wnl + j2 * 16 + c;
#pragma unroll
        for (int ks = 0; ks < 2; ks++)
            boffs[j2][ks] = rl * 64 + (((ks * 4 + g) ^ (rl & 7)) * 8);
    }

    // fused-xa1 read offsets: this wave's rows (w&3)*32 + fi*16 within half ha
    const int xrow0 = (w & 3) * 32;
    int xoffs[2][2];
#pragma unroll
    for (int fi = 0; fi < 2; fi++) {
        int rl = xrow0 + fi * 16 + c;
#pragma unroll
        for (int ks = 0; ks < 2; ks++)
            xoffs[fi][ks] = rl * 64 + (((ks * 4 + g) ^ (rl & 7)) * 8);
    }

    const int trow = t >> 3;
    const int qq   = (t & 7) ^ (trow & 7);
    const bf16_t* aO = A + (size_t)(tile_m + trow) * K + qq * 8;
    const bf16_t* wO = W + (size_t)(tile_n + trow) * K + qq * 8;
    const size_t rK64 = (size_t)64 * K;

#define STAGE_A(T, h) do {                                                         \
    load16_lds(aO + (size_t)(h) * 128 * K + (size_t)(T) * 64,                      \
               &As[((T) & 1) * 2 + (h)][t * 8]);                                   \
    load16_lds(aO + (size_t)(h) * 128 * K + rK64 + (size_t)(T) * 64,               \
               &As[((T) & 1) * 2 + (h)][4096 + t * 8]); } while (0)
#define STAGE_B(T, h) do {                                                         \
    load16_lds(wO + (size_t)(h) * 128 * K + (size_t)(T) * 64,                      \
               &Bs[((T) & 1) * 2 + (h)][t * 8]);                                   \
    load16_lds(wO + (size_t)(h) * 128 * K + rK64 + (size_t)(T) * 64,               \
               &Bs[((T) & 1) * 2 + (h)][4096 + t * 8]); } while (0)

    f32x4 acc[8][4];
#pragma unroll
    for (int i = 0; i < 8; i++)
#pragma unroll
        for (int j2 = 0; j2 < 4; j2++) {
            f32x4 z = {0.f, 0.f, 0.f, 0.f};
            acc[i][j2] = z;
        }
    f32x4 accx[2];
    {
        f32x4 z = {0.f, 0.f, 0.f, 0.f};
        accx[0] = z; accx[1] = z;
    }

    const int NT = K >> 6;

    STAGE_B(0, 0); STAGE_B(0, 1); STAGE_A(0, 0); STAGE_A(0, 1);
    WAIT_VM4();
    STAGE_B(1, 0); STAGE_B(1, 1); STAGE_A(1, 0);
    WAIT_LGKM0();   // publish Aq16 conversion before first barrier
    WAIT_VM6();
    SBAR();

    for (int j = 0; j < NT; j++) {
        const bf16_t* Ab = &As[(j & 1) * 2 + ha][0];
        const bf16_t* Bb = &Bs[(j & 1) * 2 + hb][0];
        bf16x8 bfr[4][2], af0[4], af1[4];
        bf16x8 xf0a, xf1a, xf0b, xf1b, apf0, apf1;

        // ---- P0 ----
#pragma unroll
        for (int j2 = 0; j2 < 4; j2++) {
            bfr[j2][0] = *(const bf16x8*)&Bb[boffs[j2][0]];
            bfr[j2][1] = *(const bf16x8*)&Bb[boffs[j2][1]];
        }
#pragma unroll
        for (int i = 0; i < 4; i++) af0[i] = *(const bf16x8*)&Ab[aoffs[i][0]];
        if (j + 1 < NT) STAGE_A(j + 1, 1);
        WAIT_LGKM8();
        SBAR();
        WAIT_LGKM0();
        SCHED0();
        __builtin_amdgcn_s_setprio(1);
#pragma unroll
        for (int i = 0; i < 4; i++)
#pragma unroll
            for (int j2 = 0; j2 < 4; j2++)
                acc[i][j2] = MFMA_BF16(af0[i], bfr[j2][0], acc[i][j2], 0, 0, 0);
        __builtin_amdgcn_s_setprio(0);
        SBAR();

        // ---- P1 (+ fused xa1 ks0) ----
#pragma unroll
        for (int i = 0; i < 4; i++) af1[i] = *(const bf16x8*)&Ab[aoffs[i + 4][0]];
        xf0a = *(const bf16x8*)&Ab[xoffs[0][0]];
        xf1a = *(const bf16x8*)&Ab[xoffs[1][0]];
        apf0 = *(const bf16x8*)&Aq16[(c & 7) * 1032 + j * 64 + g * 8];
        if (j + 2 < NT) STAGE_B(j + 2, 0);
        SBAR();
        WAIT_LGKM0();
        SCHED0();
        __builtin_amdgcn_s_setprio(1);
#pragma unroll
        for (int i = 0; i < 4; i++)
#pragma unroll
            for (int j2 = 0; j2 < 4; j2++)
                acc[4 + i][j2] = MFMA_BF16(af1[i], bfr[j2][0], acc[4 + i][j2], 0, 0, 0);
        accx[0] = MFMA_BF16(xf0a, apf0, accx[0], 0, 0, 0);
        accx[1] = MFMA_BF16(xf1a, apf0, accx[1], 0, 0, 0);
        __builtin_amdgcn_s_setprio(0);
        SBAR();

        // ---- P2 ----
#pragma unroll
        for (int i = 0; i < 4; i++) af0[i] = *(const bf16x8*)&Ab[aoffs[i][1]];
#pragma unroll
        for (int i = 0; i < 4; i++) af1[i] = *(const bf16x8*)&Ab[aoffs[i + 4][1]];
        xf0b = *(const bf16x8*)&Ab[xoffs[0][1]];
        xf1b = *(const bf16x8*)&Ab[xoffs[1][1]];
        apf1 = *(const bf16x8*)&Aq16[(c & 7) * 1032 + j * 64 + 32 + g * 8];
        if (j + 2 < NT) STAGE_B(j + 2, 1);
        SBAR();
        WAIT_LGKM0();
        SCHED0();
        __builtin_amdgcn_s_setprio(1);
#pragma unroll
        for (int i = 0; i < 4; i++)
#pragma unroll
            for (int j2 = 0; j2 < 4; j2++)
                acc[i][j2] = MFMA_BF16(af0[i], bfr[j2][1], acc[i][j2], 0, 0, 0);
        __builtin_amdgcn_s_setprio(0);
        SBAR();

        // ---- P3 (+ fused xa1 ks1) ----
        if (j + 2 < NT) STAGE_A(j + 2, 0);
        SBAR();
        __builtin_amdgcn_s_setprio(1);
#pragma unroll
        for (int i = 0; i < 4; i++)
#pragma unroll
            for (int j2 = 0; j2 < 4; j2++)
                acc[4 + i][j2] = MFMA_BF16(af1[i], bfr[j2][1], acc[4 + i][j2], 0, 0, 0);
        accx[0] = MFMA_BF16(xf0b, apf1, accx[0], 0, 0, 0);
        accx[1] = MFMA_BF16(xf1b, apf1, accx[1], 0, 0, 0);
        __builtin_amdgcn_s_setprio(0);
        if (j < NT - 2) WAIT_VM6(); else WAIT_VM0();
        SBAR();
    }
#undef STAGE_A
#undef STAGE_B

    // redistribute xa1 fragments via LDS (reuse As: 256 rows x 8 r x f32)
    float* xl = (float*)&As[0][0];
    if (c < 8) {
#pragma unroll
        for (int fi = 0; fi < 2; fi++)
#pragma unroll
            for (int rg = 0; rg < 4; rg++)
                xl[(ha * 128 + xrow0 + fi * 16 + g * 4 + rg) * 8 + c] = accx[fi][rg];
    }
    __syncthreads();

    const int seg    = tile_n >> 10;
    const int tn_loc = tile_n & 1023;
    bf16_t* Cout = (seg == 0) ? C0 : (seg == 1) ? C1 : C2;

    float biasf[4];
    float lbv[4][8];
#pragma unroll
    for (int j2 = 0; j2 < 4; j2++) {
        int col = tile_n + wn + j2 * 16 + c;
        biasf[j2] = bias[col];
        f32x4 lb0 = *(const f32x4*)&LB[(size_t)col * 8];
        f32x4 lb1 = *(const f32x4*)&LB[(size_t)col * 8 + 4];
#pragma unroll
        for (int r = 0; r < 4; r++) { lbv[j2][r] = lb0[r]; lbv[j2][r + 4] = lb1[r]; }
    }
#pragma unroll
    for (int i = 0; i < 8; i++) {
#pragma unroll
        for (int rg = 0; rg < 4; rg++) {
            int rloc = wm + i * 16 + g * 4 + rg;
            int row  = tile_m + rloc;
            f32x4 xa0 = *(const f32x4*)&xl[rloc * 8];
            f32x4 xa1 = *(const f32x4*)&xl[rloc * 8 + 4];
#pragma unroll
            for (int j2 = 0; j2 < 4; j2++) {
                float lora = xa0[0] * lbv[j2][0] + xa0[1] * lbv[j2][1] +
                             xa0[2] * lbv[j2][2] + xa0[3] * lbv[j2][3] +
                             xa1[0] * lbv[j2][4] + xa1[1] * lbv[j2][5] +
                             xa1[2] * lbv[j2][6] + xa1[3] * lbv[j2][7];
                float v = acc[i][j2][rg] + biasf[j2] + 2.0f * lora;
                int lcol = tn_loc + wn + j2 * 16 + c;
                if (Cf) Cf[(size_t)row * 1024 + lcol] = v;
                else    Cout[(size_t)row * 1024 + lcol] = (bf16_t)v;
            }
        }
    }
}

// ---------------------------------------------------------------------------
// Causal flash attention, QBLK=128 two-strip form (round-7, verified).
// ---------------------------------------------------------------------------
#define VT_IDX(d, kv) ((d) * 72 + ((d) >> 4) * 16 + (kv))
#define PS_IDX(q, kv) ((q) * 72 + ((q) >> 2) * 8 + (kv))
#define PW_REGION 1168

__global__ __launch_bounds__(256, 2) void attn_kernel(
    bf16_t* __restrict__ Q, const bf16_t* __restrict__ Kg,
    const bf16_t* __restrict__ Vg)
{
    __shared__ __align__(16) bf16_t Ks[64 * 72];
    __shared__ __align__(16) bf16_t Vt[64 * 72 + 64];
    __shared__ __align__(16) bf16_t Ps[8 * PW_REGION];

    const int t    = threadIdx.x;
    const int lane = t & 63;
    const int w    = t >> 6;
    const int c    = lane & 15;
    const int g    = lane >> 4;

    const int id = blockIdx.x;
    const int qb = 15 - (id >> 6);
    const int h  = id & 15;
    const int b  = (id >> 4) & 3;
    const int q0 = qb * 128;
    const size_t base = (size_t)b * 2048 * 1024;
    const int last = 2 * qb + 1;

    bf16x8 qfA[2], qfB[2];
    {
        const bf16_t* qpA = Q + base + (size_t)(q0 + w * 16 + c) * 1024 + h * 64;
        qfA[0] = *(const bf16x8*)&qpA[g * 8];
        qfA[1] = *(const bf16x8*)&qpA[32 + g * 8];
        const bf16_t* qpB = qpA + (size_t)64 * 1024;
        qfB[0] = *(const bf16x8*)&qpB[g * 8];
        qfB[1] = *(const bf16x8*)&qpB[32 + g * 8];
    }

    bf16x8 ones;
#pragma unroll
    for (int e = 0; e < 8; e++) ones[e] = (bf16_t)1.0f;

    f32x4 accA[4], accB[4];
#pragma unroll
    for (int jd = 0; jd < 4; jd++) {
        f32x4 z = {0.f, 0.f, 0.f, 0.f};
        accA[jd] = z; accB[jd] = z;
    }
    f32x4 lA = {0.f, 0.f, 0.f, 0.f};
    f32x4 lB = {0.f, 0.f, 0.f, 0.f};
    float mA = NEG_BIG, mB = NEG_BIG;

    const int sr = t >> 2;
    const int sc = (t & 3) * 16;
    const int vtbase = VT_IDX(sc, sr);

    bf16x8 kr0, kr1, vr0, vr1;
    {
        const bf16_t* kp = Kg + base + (size_t)sr * 1024 + h * 64 + sc;
        kr0 = *(const bf16x8*)&kp[0];
        kr1 = *(const bf16x8*)&kp[8];
        const bf16_t* vp = Vg + base + (size_t)sr * 1024 + h * 64 + sc;
        vr0 = *(const bf16x8*)&vp[0];
        vr1 = *(const bf16x8*)&vp[8];
    }

    bf16_t* PwA = &Ps[(w * 2 + 0) * PW_REGION];
    bf16_t* PwB = &Ps[(w * 2 + 1) * PW_REGION];
    const float SCL = 0.125f * 1.44269504088896f;

    for (int kt = 0; kt <= last; kt++) {
        if (kt > 0) __syncthreads();
        *(bf16x8*)&Ks[sr * 72 + sc]     = kr0;
        *(bf16x8*)&Ks[sr * 72 + sc + 8] = kr1;
#pragma unroll
        for (int e = 0; e < 8; e++) Vt[vtbase + e * 72]       = vr0[e];
#pragma unroll
        for (int e = 0; e < 8; e++) Vt[vtbase + (e + 8) * 72] = vr1[e];
        __syncthreads();

        if (kt < last) {
            const bf16_t* kp = Kg + base + (size_t)((kt + 1) * 64 + sr) * 1024 + h * 64 + sc;
            kr0 = *(const bf16x8*)&kp[0];
            kr1 = *(const bf16x8*)&kp[8];
            const bf16_t* vp = Vg + base + (size_t)((kt + 1) * 64 + sr) * 1024 + h * 64 + sc;
            vr0 = *(const bf16x8*)&vp[0];
            vr1 = *(const bf16x8*)&vp[8];
        }

        const bool doA = (kt <= 2 * qb);

        f32x4 sA[4], sB[4];
#pragma unroll
        for (int j = 0; j < 4; j++) {
            f32x4 z = {0.f, 0.f, 0.f, 0.f};
            sA[j] = z; sB[j] = z;
        }
#pragma unroll
        for (int kk = 0; kk < 2; kk++) {
            bf16x8 kf[4];
#pragma unroll
            for (int j = 0; j < 4; j++)
                kf[j] = *(const bf16x8*)&Ks[(j * 16 + c) * 72 + kk * 32 + g * 8];
            if (doA) {
#pragma unroll
                for (int j = 0; j < 4; j++)
                    sA[j] = MFMA_BF16(kf[j], qfA[kk], sA[j], 0, 0, 0);
            }
#pragma unroll
            for (int j = 0; j < 4; j++)
                sB[j] = MFMA_BF16(kf[j], qfB[kk], sB[j], 0, 0, 0);
        }

        if (doA) {
#pragma unroll
            for (int j = 0; j < 4; j++)
#pragma unroll
                for (int r = 0; r < 4; r++) sA[j][r] *= SCL;
            if (kt == 2 * qb) {
#pragma unroll
                for (int j = 0; j < 4; j++)
#pragma unroll
                    for (int r = 0; r < 4; r++)
                        if (j * 16 + g * 4 + r > w * 16 + c) sA[j][r] = NEG_BIG;
            }
            float mx;
            {
                float a0 = fmaxf(fmaxf(sA[0][0], sA[0][1]), fmaxf(sA[0][2], sA[0][3]));
                float a1 = fmaxf(fmaxf(sA[1][0], sA[1][1]), fmaxf(sA[1][2], sA[1][3]));
                float a2 = fmaxf(fmaxf(sA[2][0], sA[2][1]), fmaxf(sA[2][2], sA[2][3]));
                float a3 = fmaxf(fmaxf(sA[3][0], sA[3][1]), fmaxf(sA[3][2], sA[3][3]));
                mx = fmaxf(fmaxf(a0, a1), fmaxf(a2, a3));
                mx = fmaxf(mx, __shfl_xor(mx, 16));
                mx = fmaxf(mx, __shfl_xor(mx, 32));
            }
            if (!__all(mx <= mA + 8.0f)) {
                float mnew  = fmaxf(mA, mx);
                float alpha = EXP2F(mA - mnew);
                mA = mnew;
#pragma unroll
                for (int jd = 0; jd < 4; jd++)
#pragma unroll
                    for (int r = 0; r < 4; r++) accA[jd][r] *= alpha;
                lA[0] *= alpha;
            }
#pragma unroll
            for (int j = 0; j < 4; j++)
#pragma unroll
                for (int r = 0; r < 4; r++) sA[j][r] = EXP2F(sA[j][r] - mA);
#pragma unroll
            for (int j = 0; j < 4; j++) {
                bf16x4 pk;
#pragma unroll
                for (int r = 0; r < 4; r++) pk[r] = (bf16_t)sA[j][r];
                *(bf16x4*)&PwA[PS_IDX(c, j * 16 + g * 4)] = pk;
            }
        }

        {
#pragma unroll
            for (int j = 0; j < 4; j++)
#pragma unroll
                for (int r = 0; r < 4; r++) sB[j][r] *= SCL;
            if (kt == last) {
#pragma unroll
                for (int j = 0; j < 4; j++)
#pragma unroll
                    for (int r = 0; r < 4; r++)
                        if (j * 16 + g * 4 + r > w * 16 + c) sB[j][r] = NEG_BIG;
            }
            float mx;
            {
                float a0 = fmaxf(fmaxf(sB[0][0], sB[0][1]), fmaxf(sB[0][2], sB[0][3]));
                float a1 = fmaxf(fmaxf(sB[1][0], sB[1][1]), fmaxf(sB[1][2], sB[1][3]));
                float a2 = fmaxf(fmaxf(sB[2][0], sB[2][1]), fmaxf(sB[2][2], sB[2][3]));
                float a3 = fmaxf(fmaxf(sB[3][0], sB[3][1]), fmaxf(sB[3][2], sB[3][3]));
                mx = fmaxf(fmaxf(a0, a1), fmaxf(a2, a3));
                mx = fmaxf(mx, __shfl_xor(mx, 16));
                mx = fmaxf(mx, __shfl_xor(mx, 32));
            }
            if (!__all(mx <= mB + 8.0f)) {
                float mnew  = fmaxf(mB, mx);
                float alpha = EXP2F(mB - mnew);
                mB = mnew;
#pragma unroll
                for (int jd = 0; jd < 4; jd++)
#pragma unroll
                    for (int r = 0; r < 4; r++) accB[jd][r] *= alpha;
                lB[0] *= alpha;
            }
#pragma unroll
            for (int j = 0; j < 4; j++)
#pragma unroll
                for (int r = 0; r < 4; r++) sB[j][r] = EXP2F(sB[j][r] - mB);
#pragma unroll
            for (int j = 0; j < 4; j++) {
                bf16x4 pk;
#pragma unroll
                for (int r = 0; r < 4; r++) pk[r] = (bf16_t)sB[j][r];
                *(bf16x4*)&PwB[PS_IDX(c, j * 16 + g * 4)] = pk;
            }
        }

#pragma unroll
        for (int kkv = 0; kkv < 2; kkv++) {
            bf16x8 vf[4];
#pragma unroll
            for (int jd = 0; jd < 4; jd++)
                vf[jd] = *(const bf16x8*)&Vt[VT_IDX(jd * 16 + c, kkv * 32 + g * 8)];
            if (doA) {
                bf16x8 pfA = *(const bf16x8*)&PwA[PS_IDX(c, kkv * 32 + g * 8)];
#pragma unroll
                for (int jd = 0; jd < 4; jd++)
                    accA[jd] = MFMA_BF16(vf[jd], pfA, accA[jd], 0, 0, 0);
                lA = MFMA_BF16(ones, pfA, lA, 0, 0, 0);
            }
            bf16x8 pfB = *(const bf16x8*)&PwB[PS_IDX(c, kkv * 32 + g * 8)];
#pragma unroll
            for (int jd = 0; jd < 4; jd++)
                accB[jd] = MFMA_BF16(vf[jd], pfB, accB[jd], 0, 0, 0);
            lB = MFMA_BF16(ones, pfB, lB, 0, 0, 0);
        }
    }

    {
        float rl = 1.0f / lA[0];
        bf16_t* op = Q + base + (size_t)(q0 + w * 16 + c) * 1024 + h * 64;
#pragma unroll
        for (int jd = 0; jd < 4; jd++) {
            bf16x4 o4;
#pragma unroll
            for (int r = 0; r < 4; r++) o4[r] = (bf16_t)(accA[jd][r] * rl);
            *(bf16x4*)&op[jd * 16 + g * 4] = o4;
        }
    }
    {
        float rl = 1.0f / lB[0];
        bf16_t* op = Q + base + (size_t)(q0 + 64 + w * 16 + c) * 1024 + h * 64;
#pragma unroll
        for (int jd = 0; jd < 4; jd++) {
            bf16x4 o4;
#pragma unroll
            for (int r = 0; r < 4; r++) o4[r] = (bf16_t)(accB[jd][r] * rl);
            *(bf16x4*)&op[jd * 16 + g * 4] = o4;
        }
    }
}

// ---------------------------------------------------------------------------
extern "C" void kernel_launch(void* const* d_in, const int* in_sizes, int n_in,
                              void* d_out, int out_size, void* d_ws, size_t ws_size,
                              hipStream_t stream) {
    const float* x     = (const float*)d_in[0];
    const float* Wqkv  = (const float*)d_in[1];
    const float* bqkv  = (const float*)d_in[2];
    const float* Aqkv  = (const float*)d_in[3];
    const float* Bqkv  = (const float*)d_in[4];
    const float* Wproj = (const float*)d_in[5];
    const float* bproj = (const float*)d_in[6];
    const float* Aproj = (const float*)d_in[7];
    const float* Bproj = (const float*)d_in[8];
    float* out = (float*)d_out;

    char* ws = (char*)d_ws;
    const bool big = ws_size >= (size_t)(72.5 * 1024 * 1024) + 65536;

    if (big) {
        float*  xa1    = (float*)ws;
        bf16_t* x16    = (bf16_t*)(ws + 524288);
        bf16_t* Wqkv16 = x16 + (size_t)8192 * 1024;
        bf16_t* Wproj16= Wqkv16 + (size_t)3072 * 1024;
        bf16_t* Qfull  = Wproj16 + (size_t)1024 * 1024;
        bf16_t* Kfull  = Qfull + (size_t)8192 * 1024;
        bf16_t* Vfull  = Kfull + (size_t)8192 * 1024;

        // converts only (xa1 now fused into gemm_256)
        prep_kernel<<<6144, 256, 0, stream>>>(
            x, Wqkv, Wproj, x16, Wqkv16, Wproj16, Aqkv, xa1);

        // QKV GEMM with fused first-stage LoRA
        gemm_256<<<384, 512, 0, stream>>>(
            x16, Wqkv16, bqkv, Aqkv, Bqkv, Qfull, Kfull, Vfull, nullptr, 1024, 12);

        attn_kernel<<<1024, 256, 0, stream>>>(Qfull, Kfull, Vfull);

        // proj GEMM with fused second-stage LoRA
        gemm_proj_fused<<<dim3(8, 64), 256, 0, stream>>>(
            Qfull, Wproj16, bproj, Aproj, Bproj, out, 1024);
    } else {
        float*  xa1   = (float*)ws;
        float*  xa2   = (float*)(ws + 262144);
        bf16_t* Qfull = (bf16_t*)(ws + 524288);
        bf16_t* Kfull = Qfull + (size_t)8192 * 1024;
        bf16_t* Vfull = Kfull + (size_t)8192 * 1024;

        lora_xa_kernel<float><<<2048, 256, 0, stream>>>(x, Aqkv, xa1);
        gemm_bias_lora<float, float><<<dim3(24, 64), 256, 0, stream>>>(
            x, Wqkv, bqkv, xa1, Bqkv, Qfull, Kfull, Vfull, nullptr, 1024);
        attn_kernel<<<1024, 256, 0, stream>>>(Qfull, Kfull, Vfull);
        lora_xa_kernel<bf16_t><<<2048, 256, 0, stream>>>(Qfull, Aproj, xa2);
        gemm_bias_lora<bf16_t, float><<<dim3(8, 64), 256, 0, stream>>>(
            Qfull, Wproj, bproj, xa2, Bproj,
            nullptr, nullptr, nullptr, out, 1024);
    }
}

// Round 10
// 285.764 us; speedup vs baseline: 1.1948x; 1.0117x over previous
//
#include <hip/hip_runtime.h>
#include <hip/hip_bf16.h>

typedef __bf16 bf16_t;
typedef __bf16 bf16x8 __attribute__((ext_vector_type(8)));
typedef __bf16 bf16x4 __attribute__((ext_vector_type(4)));
typedef float  f32x4  __attribute__((ext_vector_type(4)));

#define MFMA_BF16 __builtin_amdgcn_mfma_f32_16x16x32_bf16
#define NEG_BIG  (-3.0e38f)

#if __has_builtin(__builtin_amdgcn_exp2f)
#define EXP2F(x) __builtin_amdgcn_exp2f(x)
#else
#define EXP2F(x) exp2f(x)
#endif

#define SBAR()       __builtin_amdgcn_s_barrier()
#define SCHED0()     __builtin_amdgcn_sched_barrier(0)
#define WAIT_LGKM0() asm volatile("s_waitcnt lgkmcnt(0)" ::: "memory")
#define WAIT_LGKM8() asm volatile("s_waitcnt lgkmcnt(8)" ::: "memory")
#define WAIT_VM0()   asm volatile("s_waitcnt vmcnt(0)" ::: "memory")
#define WAIT_VM4()   asm volatile("s_waitcnt vmcnt(4)" ::: "memory")
#define WAIT_VM6()   asm volatile("s_waitcnt vmcnt(6)" ::: "memory")

// async global->LDS 16B copy (gfx950 dwordx4 variant)
__device__ __forceinline__ void load16_lds(const bf16_t* g, bf16_t* l) {
    __builtin_amdgcn_global_load_lds(
        (const __attribute__((address_space(1))) void*)g,
        (__attribute__((address_space(3))) void*)l, 16, 0, 0);
}

// load 8 contiguous elements as bf16x8, converting if source is fp32
__device__ inline bf16x8 ld8(const bf16_t* p) { return *(const bf16x8*)p; }
__device__ inline bf16x8 ld8(const float* p) {
    f32x4 a = *(const f32x4*)p;
    f32x4 b = *(const f32x4*)(p + 4);
    bf16x8 o;
    o[0] = (bf16_t)a[0]; o[1] = (bf16_t)a[1]; o[2] = (bf16_t)a[2]; o[3] = (bf16_t)a[3];
    o[4] = (bf16_t)b[0]; o[5] = (bf16_t)b[1]; o[6] = (bf16_t)b[2]; o[7] = (bf16_t)b[3];
    return o;
}

// ---------------------------------------------------------------------------
// LoRA first stage body: out[m][r] = sum_k X[m][k] * A[r][k]
// ---------------------------------------------------------------------------
template <typename TX>
__device__ __forceinline__ void lora_xa_body(
    const TX* __restrict__ X, const float* __restrict__ A,
    float* __restrict__ out, int m, int lane)
{
    const TX* xp = X + (size_t)m * 1024;
    float acc[8];
#pragma unroll
    for (int r = 0; r < 8; r++) acc[r] = 0.f;

#pragma unroll 4
    for (int ci = 0; ci < 16; ci++) {
        int k = ci * 64 + lane;
        float xv = (float)xp[k];
#pragma unroll
        for (int r = 0; r < 8; r++) acc[r] += xv * A[r * 1024 + k];
    }
#pragma unroll
    for (int r = 0; r < 8; r++) {
        float v = acc[r];
        v += __shfl_xor(v, 1);  v += __shfl_xor(v, 2);  v += __shfl_xor(v, 4);
        v += __shfl_xor(v, 8);  v += __shfl_xor(v, 16); v += __shfl_xor(v, 32);
        if (lane == 0) out[m * 8 + r] = v;
    }
}

template <typename TX>
__global__ __launch_bounds__(256) void lora_xa_kernel(
    const TX* __restrict__ X, const float* __restrict__ A,
    float* __restrict__ out)
{
    const int lane = threadIdx.x & 63;
    const int w    = threadIdx.x >> 6;
    const int m    = blockIdx.x * 4 + w;
    lora_xa_body<TX>(X, A, out, m, lane);
}

// ---------------------------------------------------------------------------
// Prep: fp32->bf16 converts for x / Wqkv / Wproj (6144 blocks, big path).
// ---------------------------------------------------------------------------
__global__ __launch_bounds__(256) void prep_kernel(
    const float* __restrict__ x, const float* __restrict__ Wqkv,
    const float* __restrict__ Wproj,
    bf16_t* __restrict__ x16, bf16_t* __restrict__ Wqkv16,
    bf16_t* __restrict__ Wproj16,
    const float* __restrict__ Aqkv, float* __restrict__ xa1)
{
    const int bid = blockIdx.x;
    if (bid < 6144) {
        const float* in; bf16_t* out; size_t off;
        if (bid < 4096)      { in = x;     out = x16;     off = (size_t)bid * 2048; }
        else if (bid < 5632) { in = Wqkv;  out = Wqkv16;  off = (size_t)(bid - 4096) * 2048; }
        else                 { in = Wproj; out = Wproj16; off = (size_t)(bid - 5632) * 2048; }
        size_t i = off + (size_t)threadIdx.x * 8;
        *(bf16x8*)&out[i] = ld8(&in[i]);
    } else {
        const int lane = threadIdx.x & 63;
        const int w    = threadIdx.x >> 6;
        const int m    = (bid - 6144) * 4 + w;
        lora_xa_body<float>(x, Aqkv, xa1, m, lane);
    }
}

// ---------------------------------------------------------------------------
// Shared epilogue for 4x4 acc (128-tile fallback kernel)
// ---------------------------------------------------------------------------
__device__ __forceinline__ void gemm_epilogue(
    f32x4 (&acc)[4][4], const float* bias, const float* xA, const float* LB,
    bf16_t* C0, bf16_t* C1, bf16_t* C2, float* Cf,
    int tile_m, int tile_n, int wm, int wn, int c, int g)
{
    const int seg    = tile_n >> 10;
    const int tn_loc = tile_n & 1023;
    bf16_t* Cout = (seg == 0) ? C0 : (seg == 1) ? C1 : C2;

    float biasf[4];
    float lbv[4][8];
#pragma unroll
    for (int j = 0; j < 4; j++) {
        int col = tile_n + wn + j * 16 + c;
        biasf[j] = bias[col];
        f32x4 lb0 = *(const f32x4*)&LB[(size_t)col * 8];
        f32x4 lb1 = *(const f32x4*)&LB[(size_t)col * 8 + 4];
#pragma unroll
        for (int r = 0; r < 4; r++) { lbv[j][r] = lb0[r]; lbv[j][r + 4] = lb1[r]; }
    }
#pragma unroll
    for (int i = 0; i < 4; i++) {
#pragma unroll
        for (int rg = 0; rg < 4; rg++) {
            int row = tile_m + wm + i * 16 + g * 4 + rg;
            f32x4 xa0 = *(const f32x4*)&xA[(size_t)row * 8];
            f32x4 xa1 = *(const f32x4*)&xA[(size_t)row * 8 + 4];
#pragma unroll
            for (int j = 0; j < 4; j++) {
                float lora = xa0[0] * lbv[j][0] + xa0[1] * lbv[j][1] +
                             xa0[2] * lbv[j][2] + xa0[3] * lbv[j][3] +
                             xa1[0] * lbv[j][4] + xa1[1] * lbv[j][5] +
                             xa1[2] * lbv[j][6] + xa1[3] * lbv[j][7];
                float v = acc[i][j][rg] + biasf[j] + 2.0f * lora;
                int lcol = tn_loc + wn + j * 16 + c;
                if (Cf) Cf[(size_t)row * 1024 + lcol] = v;
                else    Cout[(size_t)row * 1024 + lcol] = (bf16_t)v;
            }
        }
    }
}

// ---------------------------------------------------------------------------
// FALLBACK GEMM (small-ws path): VGPR staging, inline fp32->bf16 cvt.
// ---------------------------------------------------------------------------
template <typename TA, typename TW>
__global__ __launch_bounds__(256) void gemm_bias_lora(
    const TA* __restrict__ A, const TW* __restrict__ W,
    const float* __restrict__ bias, const float* __restrict__ xA,
    const float* __restrict__ LB,
    bf16_t* __restrict__ C0, bf16_t* __restrict__ C1, bf16_t* __restrict__ C2,
    float* __restrict__ Cf, int K)
{
    __shared__ __align__(16) bf16_t As[128 * 72];
    __shared__ __align__(16) bf16_t Bs[128 * 72];

    const int t    = threadIdx.x;
    const int lane = t & 63;
    const int w    = t >> 6;
    const int wm   = (w >> 1) * 64;
    const int wn   = (w & 1) * 64;
    const int c    = lane & 15;
    const int g    = lane >> 4;
    const int tile_m = blockIdx.y * 128;
    const int tile_n = blockIdx.x * 128;

    const int srow = t >> 3;
    const int scol = (t & 7) * 8;

    f32x4 acc[4][4];
#pragma unroll
    for (int i = 0; i < 4; i++)
#pragma unroll
        for (int j = 0; j < 4; j++) {
            f32x4 z = {0.f, 0.f, 0.f, 0.f};
            acc[i][j] = z;
        }

    for (int k0 = 0; k0 < K; k0 += 64) {
#pragma unroll
        for (int i = 0; i < 4; i++) {
            int r = srow + i * 32;
            *(bf16x8*)&As[r * 72 + scol] = ld8(&A[(size_t)(tile_m + r) * K + k0 + scol]);
            *(bf16x8*)&Bs[r * 72 + scol] = ld8(&W[(size_t)(tile_n + r) * K + k0 + scol]);
        }
        __syncthreads();

#pragma unroll
        for (int kk = 0; kk < 2; kk++) {
            bf16x8 af[4], bfr[4];
#pragma unroll
            for (int i = 0; i < 4; i++)
                af[i] = *(const bf16x8*)&As[(wm + i * 16 + c) * 72 + kk * 32 + g * 8];
#pragma unroll
            for (int j = 0; j < 4; j++)
                bfr[j] = *(const bf16x8*)&Bs[(wn + j * 16 + c) * 72 + kk * 32 + g * 8];
#pragma unroll
            for (int i = 0; i < 4; i++)
#pragma unroll
                for (int j = 0; j < 4; j++)
                    acc[i][j] = MFMA_BF16(af[i], bfr[j], acc[i][j], 0, 0, 0);
        }
        __syncthreads();
    }
    gemm_epilogue(acc, bias, xA, LB, C0, C1, C2, Cf, tile_m, tile_n, wm, wn, c, g);
}

// ---------------------------------------------------------------------------
// PROJ GEMM with FUSED second-stage LoRA (round-8, verified).
// ---------------------------------------------------------------------------
#define AS_OFF(row, q) ((row) * 64 + (((q) ^ ((row) & 7)) * 8))

__global__ __launch_bounds__(256) void gemm_proj_fused(
    const bf16_t* __restrict__ A, const bf16_t* __restrict__ W,
    const float* __restrict__ bias, const float* __restrict__ Ap,
    const float* __restrict__ LB, float* __restrict__ Cf, int K)
{
    __shared__ __align__(16) bf16_t As[128 * 64];
    __shared__ __align__(16) bf16_t Bs[128 * 64];
    __shared__ __align__(16) bf16_t Ap16[8 * 1032];   // padded stride vs bank0

    const int t    = threadIdx.x;
    const int lane = t & 63;
    const int w    = t >> 6;
    const int wm   = (w >> 1) * 64;
    const int wn   = (w & 1) * 64;
    const int c    = lane & 15;
    const int g    = lane >> 4;
    const int tile_m = blockIdx.y * 128;
    const int tile_n = blockIdx.x * 128;

    // convert Aproj (8x1024 f32) -> LDS bf16 once per block
    {
        int r = t >> 5;              // 0..7
        int k = (t & 31) * 32;       // 0..992
        const float* src = Ap + (size_t)r * 1024 + k;
        bf16_t* dst = &Ap16[r * 1032 + k];
#pragma unroll
        for (int e = 0; e < 32; e += 8)
            *(bf16x8*)&dst[e] = ld8(&src[e]);
    }

    const int trow = t >> 3;                   // 0..31
    const int k8   = (t & 7) ^ (trow & 7);     // swizzled k-chunk for staging
    const bf16_t* Ab = A + (size_t)tile_m * K + k8 * 8;
    const bf16_t* Wb = W + (size_t)tile_n * K + k8 * 8;

    f32x4 acc[4][4];
#pragma unroll
    for (int i = 0; i < 4; i++)
#pragma unroll
        for (int j = 0; j < 4; j++) {
            f32x4 z = {0.f, 0.f, 0.f, 0.f};
            acc[i][j] = z;
        }
    f32x4 accx[2];   // xa2 frags: D[row = w*32 + fi*16 + g*4+rg][r = c (c<8)]
    {
        f32x4 z = {0.f, 0.f, 0.f, 0.f};
        accx[0] = z; accx[1] = z;
    }

    for (int k0 = 0; k0 < K; k0 += 64) {
#pragma unroll
        for (int i = 0; i < 4; i++) {
            int row = i * 32 + trow;
            load16_lds(&Ab[(size_t)row * K + k0], &As[(i * 256 + t) * 8]);
            load16_lds(&Wb[(size_t)row * K + k0], &Bs[(i * 256 + t) * 8]);
        }
        __syncthreads();   // drains vmcnt + lgkm (Ap16 writes on first iter)

#pragma unroll
        for (int kk = 0; kk < 2; kk++) {
            bf16x8 af[4], bfr[4];
#pragma unroll
            for (int i = 0; i < 4; i++)
                af[i] = *(const bf16x8*)&As[AS_OFF(wm + i * 16 + c, kk * 4 + g)];
#pragma unroll
            for (int j = 0; j < 4; j++)
                bfr[j] = *(const bf16x8*)&Bs[AS_OFF(wn + j * 16 + c, kk * 4 + g)];
#pragma unroll
            for (int i = 0; i < 4; i++)
#pragma unroll
                for (int j = 0; j < 4; j++)
                    acc[i][j] = MFMA_BF16(af[i], bfr[j], acc[i][j], 0, 0, 0);
            // fused xa2: rows w*32 + fi*16, B = Ap^T fragment (r on lane c)
            bf16x8 apf = *(const bf16x8*)&Ap16[(c & 7) * 1032 + k0 + kk * 32 + g * 8];
#pragma unroll
            for (int fi = 0; fi < 2; fi++) {
                bf16x8 xf = *(const bf16x8*)&As[AS_OFF(w * 32 + fi * 16 + c, kk * 4 + g)];
                accx[fi] = MFMA_BF16(xf, apf, accx[fi], 0, 0, 0);
            }
        }
        __syncthreads();
    }

    // redistribute xa2 fragments via LDS (reuse As: 128 rows x 8 r x f32)
    float* xa2l = (float*)As;
    if (c < 8) {
#pragma unroll
        for (int fi = 0; fi < 2; fi++)
#pragma unroll
            for (int rg = 0; rg < 4; rg++)
                xa2l[(w * 32 + fi * 16 + g * 4 + rg) * 8 + c] = accx[fi][rg];
    }
    __syncthreads();

    // epilogue: bias + rank-8 LoRA (xa2 from LDS) + fp32 store
    float biasf[4];
    float lbv[4][8];
#pragma unroll
    for (int j = 0; j < 4; j++) {
        int col = tile_n + wn + j * 16 + c;
        biasf[j] = bias[col];
        f32x4 lb0 = *(const f32x4*)&LB[(size_t)col * 8];
        f32x4 lb1 = *(const f32x4*)&LB[(size_t)col * 8 + 4];
#pragma unroll
        for (int r = 0; r < 4; r++) { lbv[j][r] = lb0[r]; lbv[j][r + 4] = lb1[r]; }
    }
#pragma unroll
    for (int i = 0; i < 4; i++) {
#pragma unroll
        for (int rg = 0; rg < 4; rg++) {
            int rloc = wm + i * 16 + g * 4 + rg;
            int row  = tile_m + rloc;
            f32x4 xa0 = *(const f32x4*)&xa2l[rloc * 8];
            f32x4 xa1 = *(const f32x4*)&xa2l[rloc * 8 + 4];
#pragma unroll
            for (int j = 0; j < 4; j++) {
                float lora = xa0[0] * lbv[j][0] + xa0[1] * lbv[j][1] +
                             xa0[2] * lbv[j][2] + xa0[3] * lbv[j][3] +
                             xa1[0] * lbv[j][4] + xa1[1] * lbv[j][5] +
                             xa1[2] * lbv[j][6] + xa1[3] * lbv[j][7];
                float v = acc[i][j][rg] + biasf[j] + 2.0f * lora;
                Cf[(size_t)row * 1024 + tile_n + wn + j * 16 + c] = v;
            }
        }
    }
}

// ---------------------------------------------------------------------------
// 256x256 QKV GEMM with FUSED first-stage LoRA (round-9, verified).
// ---------------------------------------------------------------------------
__global__ __launch_bounds__(512, 2) void gemm_256(
    const bf16_t* __restrict__ A, const bf16_t* __restrict__ W,
    const float* __restrict__ bias, const float* __restrict__ Aq,
    const float* __restrict__ LB,
    bf16_t* __restrict__ C0, bf16_t* __restrict__ C1, bf16_t* __restrict__ C2,
    float* __restrict__ Cf, int K, int ntn)
{
    __shared__ __align__(16) bf16_t As[4][8192];   // [buf*2+half][128*64]
    __shared__ __align__(16) bf16_t Bs[4][8192];
    __shared__ __align__(16) bf16_t Aq16[8 * 1032];

    const int t    = threadIdx.x;
    const int lane = t & 63;
    const int w    = t >> 6;
    const int c    = lane & 15;
    const int g    = lane >> 4;

    const int nwg = gridDim.x;
    const int cpx = nwg >> 3;
    const int bid = blockIdx.x;
    const int swz = (bid & 7) * cpx + (bid >> 3);
    const int tile_m = (swz / ntn) * 256;
    const int tile_n = (swz % ntn) * 256;

    const int wm  = (w >> 2) * 128;
    const int wn  = (w & 3) * 64;
    const int ha  = w >> 2;
    const int hb  = wn >> 7;
    const int wnl = wn & 127;

    // convert Aqkv (8x1024 f32) -> LDS bf16 once per block (512 thr x 16)
    {
        int r = t >> 6;              // 0..7
        int k = (t & 63) * 16;       // 0..1008
        const float* src = Aq + (size_t)r * 1024 + k;
        bf16_t* dst = &Aq16[r * 1032 + k];
        *(bf16x8*)&dst[0] = ld8(&src[0]);
        *(bf16x8*)&dst[8] = ld8(&src[8]);
    }

    int aoffs[8][2], boffs[4][2];
#pragma unroll
    for (int il = 0; il < 8; il++) {
        int rl = il * 16 + c;
#pragma unroll
        for (int ks = 0; ks < 2; ks++)
            aoffs[il][ks] = rl * 64 + (((ks * 4 + g) ^ (rl & 7)) * 8);
    }
#pragma unroll
    for (int j2 = 0; j2 < 4; j2++) {
        int rl = wnl + j2 * 16 + c;
#pragma unroll
        for (int ks = 0; ks < 2; ks++)
            boffs[j2][ks] = rl * 64 + (((ks * 4 + g) ^ (rl & 7)) * 8);
    }

    // fused-xa1 read offsets: this wave's rows (w&3)*32 + fi*16 within half ha
    const int xrow0 = (w & 3) * 32;
    int xoffs[2][2];
#pragma unroll
    for (int fi = 0; fi < 2; fi++) {
        int rl = xrow0 + fi * 16 + c;
#pragma unroll
        for (int ks = 0; ks < 2; ks++)
            xoffs[fi][ks] = rl * 64 + (((ks * 4 + g) ^ (rl & 7)) * 8);
    }

    const int trow = t >> 3;
    const int qq   = (t & 7) ^ (trow & 7);
    const bf16_t* aO = A + (size_t)(tile_m + trow) * K + qq * 8;
    const bf16_t* wO = W + (size_t)(tile_n + trow) * K + qq * 8;
    const size_t rK64 = (size_t)64 * K;

#define STAGE_A(T, h) do {                                                         \
    load16_lds(aO + (size_t)(h) * 128 * K + (size_t)(T) * 64,                      \
               &As[((T) & 1) * 2 + (h)][t * 8]);                                   \
    load16_lds(aO + (size_t)(h) * 128 * K + rK64 + (size_t)(T) * 64,               \
               &As[((T) & 1) * 2 + (h)][4096 + t * 8]); } while (0)
#define STAGE_B(T, h) do {                                                         \
    load16_lds(wO + (size_t)(h) * 128 * K + (size_t)(T) * 64,                      \
               &Bs[((T) & 1) * 2 + (h)][t * 8]);                                   \
    load16_lds(wO + (size_t)(h) * 128 * K + rK64 + (size_t)(T) * 64,               \
               &Bs[((T) & 1) * 2 + (h)][4096 + t * 8]); } while (0)

    f32x4 acc[8][4];
#pragma unroll
    for (int i = 0; i < 8; i++)
#pragma unroll
        for (int j2 = 0; j2 < 4; j2++) {
            f32x4 z = {0.f, 0.f, 0.f, 0.f};
            acc[i][j2] = z;
        }
    f32x4 accx[2];
    {
        f32x4 z = {0.f, 0.f, 0.f, 0.f};
        accx[0] = z; accx[1] = z;
    }

    const int NT = K >> 6;

    STAGE_B(0, 0); STAGE_B(0, 1); STAGE_A(0, 0); STAGE_A(0, 1);
    WAIT_VM4();
    STAGE_B(1, 0); STAGE_B(1, 1); STAGE_A(1, 0);
    WAIT_LGKM0();   // publish Aq16 conversion before first barrier
    WAIT_VM6();
    SBAR();

    for (int j = 0; j < NT; j++) {
        const bf16_t* Ab = &As[(j & 1) * 2 + ha][0];
        const bf16_t* Bb = &Bs[(j & 1) * 2 + hb][0];
        bf16x8 bfr[4][2], af0[4], af1[4];
        bf16x8 xf0a, xf1a, xf0b, xf1b, apf0, apf1;

        // ---- P0 ----
#pragma unroll
        for (int j2 = 0; j2 < 4; j2++) {
            bfr[j2][0] = *(const bf16x8*)&Bb[boffs[j2][0]];
            bfr[j2][1] = *(const bf16x8*)&Bb[boffs[j2][1]];
        }
#pragma unroll
        for (int i = 0; i < 4; i++) af0[i] = *(const bf16x8*)&Ab[aoffs[i][0]];
        if (j + 1 < NT) STAGE_A(j + 1, 1);
        WAIT_LGKM8();
        SBAR();
        WAIT_LGKM0();
        SCHED0();
        __builtin_amdgcn_s_setprio(1);
#pragma unroll
        for (int i = 0; i < 4; i++)
#pragma unroll
            for (int j2 = 0; j2 < 4; j2++)
                acc[i][j2] = MFMA_BF16(af0[i], bfr[j2][0], acc[i][j2], 0, 0, 0);
        __builtin_amdgcn_s_setprio(0);
        SBAR();

        // ---- P1 (+ fused xa1 ks0) ----
#pragma unroll
        for (int i = 0; i < 4; i++) af1[i] = *(const bf16x8*)&Ab[aoffs[i + 4][0]];
        xf0a = *(const bf16x8*)&Ab[xoffs[0][0]];
        xf1a = *(const bf16x8*)&Ab[xoffs[1][0]];
        apf0 = *(const bf16x8*)&Aq16[(c & 7) * 1032 + j * 64 + g * 8];
        if (j + 2 < NT) STAGE_B(j + 2, 0);
        SBAR();
        WAIT_LGKM0();
        SCHED0();
        __builtin_amdgcn_s_setprio(1);
#pragma unroll
        for (int i = 0; i < 4; i++)
#pragma unroll
            for (int j2 = 0; j2 < 4; j2++)
                acc[4 + i][j2] = MFMA_BF16(af1[i], bfr[j2][0], acc[4 + i][j2], 0, 0, 0);
        accx[0] = MFMA_BF16(xf0a, apf0, accx[0], 0, 0, 0);
        accx[1] = MFMA_BF16(xf1a, apf0, accx[1], 0, 0, 0);
        __builtin_amdgcn_s_setprio(0);
        SBAR();

        // ---- P2 ----
#pragma unroll
        for (int i = 0; i < 4; i++) af0[i] = *(const bf16x8*)&Ab[aoffs[i][1]];
#pragma unroll
        for (int i = 0; i < 4; i++) af1[i] = *(const bf16x8*)&Ab[aoffs[i + 4][1]];
        xf0b = *(const bf16x8*)&Ab[xoffs[0][1]];
        xf1b = *(const bf16x8*)&Ab[xoffs[1][1]];
        apf1 = *(const bf16x8*)&Aq16[(c & 7) * 1032 + j * 64 + 32 + g * 8];
        if (j + 2 < NT) STAGE_B(j + 2, 1);
        SBAR();
        WAIT_LGKM0();
        SCHED0();
        __builtin_amdgcn_s_setprio(1);
#pragma unroll
        for (int i = 0; i < 4; i++)
#pragma unroll
            for (int j2 = 0; j2 < 4; j2++)
                acc[i][j2] = MFMA_BF16(af0[i], bfr[j2][1], acc[i][j2], 0, 0, 0);
        __builtin_amdgcn_s_setprio(0);
        SBAR();

        // ---- P3 (+ fused xa1 ks1) ----
        if (j + 2 < NT) STAGE_A(j + 2, 0);
        SBAR();
        __builtin_amdgcn_s_setprio(1);
#pragma unroll
        for (int i = 0; i < 4; i++)
#pragma unroll
            for (int j2 = 0; j2 < 4; j2++)
                acc[4 + i][j2] = MFMA_BF16(af1[i], bfr[j2][1], acc[4 + i][j2], 0, 0, 0);
        accx[0] = MFMA_BF16(xf0b, apf1, accx[0], 0, 0, 0);
        accx[1] = MFMA_BF16(xf1b, apf1, accx[1], 0, 0, 0);
        __builtin_amdgcn_s_setprio(0);
        if (j < NT - 2) WAIT_VM6(); else WAIT_VM0();
        SBAR();
    }
#undef STAGE_A
#undef STAGE_B

    // redistribute xa1 fragments via LDS (reuse As: 256 rows x 8 r x f32)
    float* xl = (float*)&As[0][0];
    if (c < 8) {
#pragma unroll
        for (int fi = 0; fi < 2; fi++)
#pragma unroll
            for (int rg = 0; rg < 4; rg++)
                xl[(ha * 128 + xrow0 + fi * 16 + g * 4 + rg) * 8 + c] = accx[fi][rg];
    }
    __syncthreads();

    const int seg    = tile_n >> 10;
    const int tn_loc = tile_n & 1023;
    bf16_t* Cout = (seg == 0) ? C0 : (seg == 1) ? C1 : C2;

    float biasf[4];
    float lbv[4][8];
#pragma unroll
    for (int j2 = 0; j2 < 4; j2++) {
        int col = tile_n + wn + j2 * 16 + c;
        biasf[j2] = bias[col];
        f32x4 lb0 = *(const f32x4*)&LB[(size_t)col * 8];
        f32x4 lb1 = *(const f32x4*)&LB[(size_t)col * 8 + 4];
#pragma unroll
        for (int r = 0; r < 4; r++) { lbv[j2][r] = lb0[r]; lbv[j2][r + 4] = lb1[r]; }
    }
#pragma unroll
    for (int i = 0; i < 8; i++) {
#pragma unroll
        for (int rg = 0; rg < 4; rg++) {
            int rloc = wm + i * 16 + g * 4 + rg;
            int row  = tile_m + rloc;
            f32x4 xa0 = *(const f32x4*)&xl[rloc * 8];
            f32x4 xa1 = *(const f32x4*)&xl[rloc * 8 + 4];
#pragma unroll
            for (int j2 = 0; j2 < 4; j2++) {
                float lora = xa0[0] * lbv[j2][0] + xa0[1] * lbv[j2][1] +
                             xa0[2] * lbv[j2][2] + xa0[3] * lbv[j2][3] +
                             xa1[0] * lbv[j2][4] + xa1[1] * lbv[j2][5] +
                             xa1[2] * lbv[j2][6] + xa1[3] * lbv[j2][7];
                float v = acc[i][j2][rg] + biasf[j2] + 2.0f * lora;
                int lcol = tn_loc + wn + j2 * 16 + c;
                if (Cf) Cf[(size_t)row * 1024 + lcol] = v;
                else    Cout[(size_t)row * 1024 + lcol] = (bf16_t)v;
            }
        }
    }
}

// ---------------------------------------------------------------------------
// Causal flash attention, QBLK=128 two-strip, KVBLK=128 (round-10).
//   KV tiles of 128 rows: kt = 0..qb (qb = 128-row q-block index).  Iteration
//   count halves vs KVBLK=64 (8704 total).  Per iter per wave: 32 QK^T MFMA
//   + 40 PV MFMA.  Mask only at the diagonal tile kt==qb (uniform expr;
//   strip A's kv>=64 fragments auto-mask).  Vt stride 136 elems (=68 words
//   == 4 banks mod 32 — same bank-step as the verified 72) + r7 rotation.
//   Ps stride 136 with (q>>2)*8 rotation.  LDS ~70KB -> 2 blocks/CU.
// ---------------------------------------------------------------------------
#define VT_IDX(d, kv) ((d) * 136 + ((d) >> 4) * 16 + (kv))
#define PS_IDX(q, kv) ((q) * 136 + ((q) >> 2) * 8 + (kv))
#define PW_REGION 2208

__global__ __launch_bounds__(256, 2) void attn_kernel(
    bf16_t* __restrict__ Q, const bf16_t* __restrict__ Kg,
    const bf16_t* __restrict__ Vg)
{
    __shared__ __align__(16) bf16_t Ks[128 * 72];
    __shared__ __align__(16) bf16_t Vt[64 * 136 + 64];
    __shared__ __align__(16) bf16_t Ps[8 * PW_REGION];

    const int t    = threadIdx.x;
    const int lane = t & 63;
    const int w    = t >> 6;
    const int c    = lane & 15;
    const int g    = lane >> 4;

    const int id = blockIdx.x;
    const int qb = 15 - (id >> 6);          // 128-row q-block, longest first
    const int h  = id & 15;
    const int b  = (id >> 4) & 3;
    const int q0 = qb * 128;
    const size_t base = (size_t)b * 2048 * 1024;

    bf16x8 qfA[2], qfB[2];
    {
        const bf16_t* qpA = Q + base + (size_t)(q0 + w * 16 + c) * 1024 + h * 64;
        qfA[0] = *(const bf16x8*)&qpA[g * 8];
        qfA[1] = *(const bf16x8*)&qpA[32 + g * 8];
        const bf16_t* qpB = qpA + (size_t)64 * 1024;
        qfB[0] = *(const bf16x8*)&qpB[g * 8];
        qfB[1] = *(const bf16x8*)&qpB[32 + g * 8];
    }

    bf16x8 ones;
#pragma unroll
    for (int e = 0; e < 8; e++) ones[e] = (bf16_t)1.0f;

    f32x4 accA[4], accB[4];
#pragma unroll
    for (int jd = 0; jd < 4; jd++) {
        f32x4 z = {0.f, 0.f, 0.f, 0.f};
        accA[jd] = z; accB[jd] = z;
    }
    f32x4 lA = {0.f, 0.f, 0.f, 0.f};
    f32x4 lB = {0.f, 0.f, 0.f, 0.f};
    float mA = NEG_BIG, mB = NEG_BIG;

    // staging: thread -> kv-row sr (0..127), 32-col half sc2 (0 or 32)
    const int sr  = t >> 1;
    const int sc2 = (t & 1) * 32;

    bf16x8 kr[4], vr[4];
    {
        const bf16_t* kp = Kg + base + (size_t)sr * 1024 + h * 64 + sc2;
        const bf16_t* vp = Vg + base + (size_t)sr * 1024 + h * 64 + sc2;
#pragma unroll
        for (int e = 0; e < 4; e++) {
            kr[e] = *(const bf16x8*)&kp[e * 8];
            vr[e] = *(const bf16x8*)&vp[e * 8];
        }
    }

    bf16_t* PwA = &Ps[(w * 2 + 0) * PW_REGION];
    bf16_t* PwB = &Ps[(w * 2 + 1) * PW_REGION];
    const float SCL = 0.125f * 1.44269504088896f;

    for (int kt = 0; kt <= qb; kt++) {
        if (kt > 0) __syncthreads();
        // K rows: [sr][sc2..sc2+31]
#pragma unroll
        for (int e = 0; e < 4; e++)
            *(bf16x8*)&Ks[sr * 72 + sc2 + e * 8] = kr[e];
        // V transpose: Vt[d = sc2+e][kv = sr]
#pragma unroll
        for (int ee = 0; ee < 4; ee++)
#pragma unroll
            for (int e2 = 0; e2 < 8; e2++) {
                int d = sc2 + ee * 8 + e2;
                Vt[VT_IDX(d, sr)] = vr[ee][e2];
            }
        __syncthreads();

        if (kt < qb) {
            const bf16_t* kp = Kg + base + (size_t)((kt + 1) * 128 + sr) * 1024 + h * 64 + sc2;
            const bf16_t* vp = Vg + base + (size_t)((kt + 1) * 128 + sr) * 1024 + h * 64 + sc2;
#pragma unroll
            for (int e = 0; e < 4; e++) {
                kr[e] = *(const bf16x8*)&kp[e * 8];
                vr[e] = *(const bf16x8*)&vp[e * 8];
            }
        }

        // S^T = K * Q^T, both strips, 8 kv-fragments
        f32x4 sA[8], sB[8];
#pragma unroll
        for (int j = 0; j < 8; j++) {
            f32x4 z = {0.f, 0.f, 0.f, 0.f};
            sA[j] = z; sB[j] = z;
        }
#pragma unroll
        for (int kk = 0; kk < 2; kk++) {
#pragma unroll
            for (int j = 0; j < 8; j++) {
                bf16x8 kf = *(const bf16x8*)&Ks[(j * 16 + c) * 72 + kk * 32 + g * 8];
                sA[j] = MFMA_BF16(kf, qfA[kk], sA[j], 0, 0, 0);
                sB[j] = MFMA_BF16(kf, qfB[kk], sB[j], 0, 0, 0);
            }
        }

        // scale
#pragma unroll
        for (int j = 0; j < 8; j++)
#pragma unroll
            for (int r = 0; r < 4; r++) { sA[j][r] *= SCL; sB[j][r] *= SCL; }

        // diagonal-tile masks (uniform; A's kv>=64 frags auto-mask)
        if (kt == qb) {
#pragma unroll
            for (int j = 0; j < 8; j++)
#pragma unroll
                for (int r = 0; r < 4; r++) {
                    int kvl = j * 16 + g * 4 + r;
                    if (kvl > w * 16 + c)      sA[j][r] = NEG_BIG;
                    if (kvl > 64 + w * 16 + c) sB[j][r] = NEG_BIG;
                }
        }

        // ---- strip A softmax ----
        {
            float mx = sA[0][0];
#pragma unroll
            for (int j = 0; j < 8; j++)
#pragma unroll
                for (int r = 0; r < 4; r++) mx = fmaxf(mx, sA[j][r]);
            mx = fmaxf(mx, __shfl_xor(mx, 16));
            mx = fmaxf(mx, __shfl_xor(mx, 32));
            if (!__all(mx <= mA + 8.0f)) {
                float mnew  = fmaxf(mA, mx);
                float alpha = EXP2F(mA - mnew);
                mA = mnew;
#pragma unroll
                for (int jd = 0; jd < 4; jd++)
#pragma unroll
                    for (int r = 0; r < 4; r++) accA[jd][r] *= alpha;
                lA[0] *= alpha;
            }
#pragma unroll
            for (int j = 0; j < 8; j++)
#pragma unroll
                for (int r = 0; r < 4; r++) sA[j][r] = EXP2F(sA[j][r] - mA);
#pragma unroll
            for (int j = 0; j < 8; j++) {
                bf16x4 pk;
#pragma unroll
                for (int r = 0; r < 4; r++) pk[r] = (bf16_t)sA[j][r];
                *(bf16x4*)&PwA[PS_IDX(c, j * 16 + g * 4)] = pk;
            }
        }

        // ---- strip B softmax ----
        {
            float mx = sB[0][0];
#pragma unroll
            for (int j = 0; j < 8; j++)
#pragma unroll
                for (int r = 0; r < 4; r++) mx = fmaxf(mx, sB[j][r]);
            mx = fmaxf(mx, __shfl_xor(mx, 16));
            mx = fmaxf(mx, __shfl_xor(mx, 32));
            if (!__all(mx <= mB + 8.0f)) {
                float mnew  = fmaxf(mB, mx);
                float alpha = EXP2F(mB - mnew);
                mB = mnew;
#pragma unroll
                for (int jd = 0; jd < 4; jd++)
#pragma unroll
                    for (int r = 0; r < 4; r++) accB[jd][r] *= alpha;
                lB[0] *= alpha;
            }
#pragma unroll
            for (int j = 0; j < 8; j++)
#pragma unroll
                for (int r = 0; r < 4; r++) sB[j][r] = EXP2F(sB[j][r] - mB);
#pragma unroll
            for (int j = 0; j < 8; j++) {
                bf16x4 pk;
#pragma unroll
                for (int r = 0; r < 4; r++) pk[r] = (bf16_t)sB[j][r];
                *(bf16x4*)&PwB[PS_IDX(c, j * 16 + g * 4)] = pk;
            }
        }

        // ---- PV: O^T += V^T * P^T, 4 kv-slices; V-frags shared ----
#pragma unroll
        for (int kkv = 0; kkv < 4; kkv++) {
            bf16x8 pfA = *(const bf16x8*)&PwA[PS_IDX(c, kkv * 32 + g * 8)];
            bf16x8 pfB = *(const bf16x8*)&PwB[PS_IDX(c, kkv * 32 + g * 8)];
#pragma unroll
            for (int jd = 0; jd < 4; jd++) {
                bf16x8 vf = *(const bf16x8*)&Vt[VT_IDX(jd * 16 + c, kkv * 32 + g * 8)];
                accA[jd] = MFMA_BF16(vf, pfA, accA[jd], 0, 0, 0);
                accB[jd] = MFMA_BF16(vf, pfB, accB[jd], 0, 0, 0);
            }
            lA = MFMA_BF16(ones, pfA, lA, 0, 0, 0);
            lB = MFMA_BF16(ones, pfB, lB, 0, 0, 0);
        }
    }

    // epilogue: packed 8B stores, both strips
    {
        float rl = 1.0f / lA[0];
        bf16_t* op = Q + base + (size_t)(q0 + w * 16 + c) * 1024 + h * 64;
#pragma unroll
        for (int jd = 0; jd < 4; jd++) {
            bf16x4 o4;
#pragma unroll
            for (int r = 0; r < 4; r++) o4[r] = (bf16_t)(accA[jd][r] * rl);
            *(bf16x4*)&op[jd * 16 + g * 4] = o4;
        }
    }
    {
        float rl = 1.0f / lB[0];
        bf16_t* op = Q + base + (size_t)(q0 + 64 + w * 16 + c) * 1024 + h * 64;
#pragma unroll
        for (int jd = 0; jd < 4; jd++) {
            bf16x4 o4;
#pragma unroll
            for (int r = 0; r < 4; r++) o4[r] = (bf16_t)(accB[jd][r] * rl);
            *(bf16x4*)&op[jd * 16 + g * 4] = o4;
        }
    }
}

// ---------------------------------------------------------------------------
extern "C" void kernel_launch(void* const* d_in, const int* in_sizes, int n_in,
                              void* d_out, int out_size, void* d_ws, size_t ws_size,
                              hipStream_t stream) {
    const float* x     = (const float*)d_in[0];
    const float* Wqkv  = (const float*)d_in[1];
    const float* bqkv  = (const float*)d_in[2];
    const float* Aqkv  = (const float*)d_in[3];
    const float* Bqkv  = (const float*)d_in[4];
    const float* Wproj = (const float*)d_in[5];
    const float* bproj = (const float*)d_in[6];
    const float* Aproj = (const float*)d_in[7];
    const float* Bproj = (const float*)d_in[8];
    float* out = (float*)d_out;

    char* ws = (char*)d_ws;
    const bool big = ws_size >= (size_t)(72.5 * 1024 * 1024) + 65536;

    if (big) {
        float*  xa1    = (float*)ws;
        bf16_t* x16    = (bf16_t*)(ws + 524288);
        bf16_t* Wqkv16 = x16 + (size_t)8192 * 1024;
        bf16_t* Wproj16= Wqkv16 + (size_t)3072 * 1024;
        bf16_t* Qfull  = Wproj16 + (size_t)1024 * 1024;
        bf16_t* Kfull  = Qfull + (size_t)8192 * 1024;
        bf16_t* Vfull  = Kfull + (size_t)8192 * 1024;

        // converts only (xa1 fused into gemm_256)
        prep_kernel<<<6144, 256, 0, stream>>>(
            x, Wqkv, Wproj, x16, Wqkv16, Wproj16, Aqkv, xa1);

        // QKV GEMM with fused first-stage LoRA
        gemm_256<<<384, 512, 0, stream>>>(
            x16, Wqkv16, bqkv, Aqkv, Bqkv, Qfull, Kfull, Vfull, nullptr, 1024, 12);

        attn_kernel<<<1024, 256, 0, stream>>>(Qfull, Kfull, Vfull);

        // proj GEMM with fused second-stage LoRA
        gemm_proj_fused<<<dim3(8, 64), 256, 0, stream>>>(
            Qfull, Wproj16, bproj, Aproj, Bproj, out, 1024);
    } else {
        float*  xa1   = (float*)ws;
        float*  xa2   = (float*)(ws + 262144);
        bf16_t* Qfull = (bf16_t*)(ws + 524288);
        bf16_t* Kfull = Qfull + (size_t)8192 * 1024;
        bf16_t* Vfull = Kfull + (size_t)8192 * 1024;

        lora_xa_kernel<float><<<2048, 256, 0, stream>>>(x, Aqkv, xa1);
        gemm_bias_lora<float, float><<<dim3(24, 64), 256, 0, stream>>>(
            x, Wqkv, bqkv, xa1, Bqkv, Qfull, Kfull, Vfull, nullptr, 1024);
        attn_kernel<<<1024, 256, 0, stream>>>(Qfull, Kfull, Vfull);
        lora_xa_kernel<bf16_t><<<2048, 256, 0, stream>>>(Qfull, Aproj, xa2);
        gemm_bias_lora<bf16_t, float><<<dim3(8, 64), 256, 0, stream>>>(
            Qfull, Wproj, bproj, xa2, Bproj,
            nullptr, nullptr, nullptr, out, 1024);
    }
}